// Round 1
// baseline (1206.746 us; speedup 1.0000x reference)
//
#include <hip/hip_runtime.h>

using u16 = unsigned short;

__device__ __forceinline__ float b2f(u16 u){ union{unsigned u; float f;} c; c.u = ((unsigned)u) << 16; return c.f; }
__device__ __forceinline__ u16 f2b(float f){
  union{float f; unsigned u;} c; c.f = f;
  unsigned r = 0x7fffu + ((c.u >> 16) & 1u);
  return (u16)((c.u + r) >> 16);
}
__device__ __forceinline__ float lo2f(unsigned u){ union{unsigned u; float f;} c; c.u = u << 16; return c.f; }
__device__ __forceinline__ float hi2f(unsigned u){ union{unsigned u; float f;} c; c.u = u & 0xffff0000u; return c.f; }

// ---------- f32 -> bf16 convert, 4/thread ----------
__global__ void k_cvt(const float4* __restrict__ in, ushort4* __restrict__ out, int n4){
  int i = blockIdx.x * 256 + threadIdx.x;
  if (i < n4){
    float4 v = in[i];
    ushort4 o; o.x = f2b(v.x); o.y = f2b(v.y); o.z = f2b(v.z); o.w = f2b(v.w);
    out[i] = o;
  }
}

// ---------- W_comb = w_lin @ w_out (bf16), b_comb = w_lin@b_out + b_lin ----------
__global__ __launch_bounds__(256) void k_prepw(const float* __restrict__ w_lin, const float* __restrict__ w_out,
    const float* __restrict__ b_out, const float* __restrict__ b_lin,
    u16* __restrict__ wc, float* __restrict__ bc){
  int l = blockIdx.x, i = threadIdx.x;
  float s = 0.f;
  for (int j = 0; j < 256; ++j) s += w_lin[l*256 + j] * w_out[j*256 + i];
  wc[l*256 + i] = f2b(s);
  __shared__ float red[256];
  red[i] = w_lin[l*256 + i] * b_out[i];
  __syncthreads();
  for (int off = 128; off > 0; off >>= 1){ if (i < off) red[i] += red[i + off]; __syncthreads(); }
  if (i == 0) bc[l] = red[0] + b_lin[l];
}

// ---------- bf16-in fp32-acc tiled GEMM: C[M,N] = A[M,K] @ B[N,K]^T ----------
// 128x128 tile, BK=16, 256 threads, 8x8 micro-tile.
// Cf!=null: float out + bias[col] + resid[row*N+col]; else bf16 out to Cb.
__global__ __launch_bounds__(256) void k_gemm(const u16* __restrict__ A, const u16* __restrict__ B,
    u16* __restrict__ Cb, float* __restrict__ Cf,
    const float* __restrict__ bias, const float* __restrict__ resid,
    int M, int N, int K){
  __shared__ float As[16][128];
  __shared__ float Bs[16][128];
  const int t = threadIdx.x;
  const int bm = blockIdx.x * 128;
  const int bn = blockIdx.y * 128;
  const int lr = t >> 1;            // 0..127
  const int lk = (t & 1) * 8;       // 0 or 8
  const int tx = t & 15, ty = t >> 4;
  const int r0 = ty * 8, c0 = tx * 8;
  float acc[8][8] = {};
  uint4 av = *(const uint4*)&A[(size_t)(bm + lr) * K + lk];
  uint4 bv = *(const uint4*)&B[(size_t)(bn + lr) * K + lk];
  for (int k0 = 0; k0 < K; k0 += 16){
    __syncthreads();
    As[lk+0][lr] = lo2f(av.x); As[lk+1][lr] = hi2f(av.x);
    As[lk+2][lr] = lo2f(av.y); As[lk+3][lr] = hi2f(av.y);
    As[lk+4][lr] = lo2f(av.z); As[lk+5][lr] = hi2f(av.z);
    As[lk+6][lr] = lo2f(av.w); As[lk+7][lr] = hi2f(av.w);
    Bs[lk+0][lr] = lo2f(bv.x); Bs[lk+1][lr] = hi2f(bv.x);
    Bs[lk+2][lr] = lo2f(bv.y); Bs[lk+3][lr] = hi2f(bv.y);
    Bs[lk+4][lr] = lo2f(bv.z); Bs[lk+5][lr] = hi2f(bv.z);
    Bs[lk+6][lr] = lo2f(bv.w); Bs[lk+7][lr] = hi2f(bv.w);
    __syncthreads();
    if (k0 + 16 < K){
      av = *(const uint4*)&A[(size_t)(bm + lr) * K + k0 + 16 + lk];
      bv = *(const uint4*)&B[(size_t)(bn + lr) * K + k0 + 16 + lk];
    }
    #pragma unroll
    for (int kk = 0; kk < 16; ++kk){
      float4 a0 = *(const float4*)&As[kk][r0];
      float4 a1 = *(const float4*)&As[kk][r0 + 4];
      float4 b0 = *(const float4*)&Bs[kk][c0];
      float4 b1 = *(const float4*)&Bs[kk][c0 + 4];
      float ar[8] = {a0.x,a0.y,a0.z,a0.w,a1.x,a1.y,a1.z,a1.w};
      float br[8] = {b0.x,b0.y,b0.z,b0.w,b1.x,b1.y,b1.z,b1.w};
      #pragma unroll
      for (int i = 0; i < 8; ++i)
        #pragma unroll
        for (int j = 0; j < 8; ++j)
          acc[i][j] += ar[i] * br[j];
    }
  }
  if (Cf){
    #pragma unroll
    for (int i = 0; i < 8; ++i){
      size_t row = (size_t)(bm + r0 + i);
      size_t base = row * N + bn + c0;
      #pragma unroll
      for (int j = 0; j < 8; ++j){
        int col = bn + c0 + j;
        Cf[base + j] = acc[i][j] + bias[col] + resid[base + j];
      }
    }
  } else {
    #pragma unroll
    for (int i = 0; i < 8; ++i){
      size_t row = (size_t)(bm + r0 + i);
      ushort4 o1, o2;
      o1.x=f2b(acc[i][0]); o1.y=f2b(acc[i][1]); o1.z=f2b(acc[i][2]); o1.w=f2b(acc[i][3]);
      o2.x=f2b(acc[i][4]); o2.y=f2b(acc[i][5]); o2.z=f2b(acc[i][6]); o2.w=f2b(acc[i][7]);
      *(ushort4*)&Cb[row * N + bn + c0]     = o1;
      *(ushort4*)&Cb[row * N + bn + c0 + 4] = o2;
    }
  }
}

// ---------- k softmax stats over n (per frame, per channel) ----------
// grid (H=8, nf); 256 thr: c = t&31 channel-in-head, r = t>>5 stripe
__global__ __launch_bounds__(256) void k_kstats(const u16* __restrict__ qkv,
    float* __restrict__ kmax, float* __restrict__ kiz){
  const int h = blockIdx.x, frel = blockIdx.y;
  const int t = threadIdx.x;
  const int c = t & 31, r = t >> 5;
  const u16* base = qkv + (size_t)frel * 9216 * 768 + 256 + h * 32;
  float m = -1e30f;
  for (int n = r; n < 9216; n += 8) m = fmaxf(m, b2f(base[(size_t)n * 768 + c]));
  __shared__ float red[8][32];
  red[r][c] = m; __syncthreads();
  if (r == 0){
    float mm = red[0][c];
    #pragma unroll
    for (int i = 1; i < 8; ++i) mm = fmaxf(mm, red[i][c]);
    red[0][c] = mm;
  }
  __syncthreads();
  const float mx = red[0][c];
  __syncthreads();
  float s = 0.f;
  for (int n = r; n < 9216; n += 8) s += __expf(b2f(base[(size_t)n * 768 + c]) - mx);
  red[r][c] = s; __syncthreads();
  if (r == 0){
    float ss = red[0][c];
    #pragma unroll
    for (int i = 1; i < 8; ++i) ss += red[i][c];
    kmax[frel*256 + h*32 + c] = mx;
    kiz [frel*256 + h*32 + c] = 1.0f / ss;
  }
}

// ---------- ctx partials: ctx[dd,e] += softmax_k[dd,n] * v[e,n] ----------
// grid (H=8, nf, S=4); each block does 2304 tokens
__global__ __launch_bounds__(256) void k_ctx(const u16* __restrict__ qkv,
    const float* __restrict__ kmax, const float* __restrict__ kiz, float* __restrict__ ctxp){
  const int h = blockIdx.x, frel = blockIdx.y, s = blockIdx.z;
  const int t = threadIdx.x;
  const int lc = t & 31, lrow = t >> 5;
  const int e4 = (t & 7) * 4, dd = t >> 3;
  __shared__ float Ks[64][32];
  __shared__ float Vs[64][32];
  const u16* kb = qkv + (size_t)frel * 9216 * 768 + 256 + h * 32;
  const u16* vb = kb + 256;
  const float mx = kmax[frel*256 + h*32 + lc];
  const float iz = kiz [frel*256 + h*32 + lc];
  float acc0=0.f, acc1=0.f, acc2=0.f, acc3=0.f;
  const int nend = (s + 1) * 2304;
  for (int n0 = s * 2304; n0 < nend; n0 += 64){
    __syncthreads();
    #pragma unroll
    for (int ii = 0; ii < 8; ++ii){
      int nl = lrow + 8*ii;
      size_t off = (size_t)(n0 + nl) * 768;
      Ks[nl][lc] = __expf(b2f(kb[off + lc]) - mx) * iz;
      Vs[nl][lc] = b2f(vb[off + lc]);
    }
    __syncthreads();
    #pragma unroll
    for (int nn = 0; nn < 64; ++nn){
      float p = Ks[nn][dd];
      float4 v = *(const float4*)&Vs[nn][e4];
      acc0 += p*v.x; acc1 += p*v.y; acc2 += p*v.z; acc3 += p*v.w;
    }
  }
  float* cb = ctxp + (((size_t)frel*4 + s)*8 + h)*1024 + dd*32 + e4;
  cb[0]=acc0; cb[1]=acc1; cb[2]=acc2; cb[3]=acc3;
}

__global__ void k_ctxred(const float* __restrict__ ctxp, float* __restrict__ ctx){
  int frel = blockIdx.x, t = threadIdx.x;
  for (int i = t; i < 8192; i += 256){
    float s = 0.f;
    #pragma unroll
    for (int q = 0; q < 4; ++q) s += ctxp[((size_t)frel*4 + q)*8192 + i];
    ctx[(size_t)frel*8192 + i] = s;
  }
}

// ---------- per-token: q channel-softmax*scale, A = ctx^T applied ----------
// grid (9216/36=256, nf); 256 thr; thread t <-> channel c=t; 36 tokens/block
__global__ __launch_bounds__(256) void k_attn(const u16* __restrict__ qkv,
    const float* __restrict__ ctx, u16* __restrict__ Ab){
  const int frel = blockIdx.y;
  const int tb = blockIdx.x * 36;
  const int t = threadIdx.x;
  const int lane = t & 63;
  const int c = t, h = c >> 5, e = c & 31;
  __shared__ float cs[8192];
  for (int i = t; i < 8192; i += 256) cs[i] = ctx[(size_t)frel*8192 + i];
  __syncthreads();
  const float scale = 0.17677669529663689f;
  const float* ch = &cs[h*1024 + e];
  for (int tk = 0; tk < 36; ++tk){
    size_t tok = (size_t)frel * 9216 + tb + tk;
    float q = b2f(qkv[tok * 768 + c]);
    float m = q;
    #pragma unroll
    for (int off = 16; off > 0; off >>= 1) m = fmaxf(m, __shfl_xor(m, off, 64));
    float p = __expf(q - m);
    float s = p;
    #pragma unroll
    for (int off = 16; off > 0; off >>= 1) s += __shfl_xor(s, off, 64);
    float qsm = p / s * scale;
    float acc = 0.f;
    #pragma unroll
    for (int dd = 0; dd < 32; ++dd){
      float qv = __shfl(qsm, (lane & 32) + dd, 64);
      acc += qv * ch[dd * 32];
    }
    Ab[tok * 256 + c] = f2b(acc);
  }
}

extern "C" void kernel_launch(void* const* d_in, const int* in_sizes, int n_in,
                              void* d_out, int out_size, void* d_ws, size_t ws_size,
                              hipStream_t stream){
  const float* x     = (const float*)d_in[0];
  const float* w_qkv = (const float*)d_in[1];
  const float* w_out = (const float*)d_in[2];
  const float* b_out = (const float*)d_in[3];
  const float* w_lin = (const float*)d_in[4];
  const float* b_lin = (const float*)d_in[5];
  float* out = (float*)d_out;

  char* p = (char*)d_ws;
  u16*   wqb   = (u16*)p;   p += (size_t)768*256*2;
  u16*   wc    = (u16*)p;   p += (size_t)256*256*2;
  float* bc    = (float*)p; p += 256*4;
  float* kmaxb = (float*)p; p += 8*256*4;
  float* kizb  = (float*)p; p += 8*256*4;
  float* ctxpb = (float*)p; p += (size_t)8*4*8192*4;
  float* ctxb  = (float*)p; p += (size_t)8*8192*4;
  size_t fixed = (size_t)(p - (char*)d_ws);
  size_t per_frame = (size_t)9216*256*2 + (size_t)9216*768*2 + (size_t)9216*256*2;
  int chunk = (ws_size >= fixed + 8*per_frame) ? 8 : 1;
  u16* xb   = (u16*)p;
  u16* qkvb = xb   + (size_t)chunk*9216*256;
  u16* Ab   = qkvb + (size_t)chunk*9216*768;

  // weight prep (once)
  hipLaunchKernelGGL(k_cvt, dim3(192), dim3(256), 0, stream, (const float4*)w_qkv, (ushort4*)wqb, 49152);
  hipLaunchKernelGGL(k_prepw, dim3(256), dim3(256), 0, stream, w_lin, w_out, b_out, b_lin, wc, bc);

  for (int f0 = 0; f0 < 8; f0 += chunk){
    const float* xc = x  + (size_t)f0*9216*256;
    float*       oc = out + (size_t)f0*9216*256;
    const int M = chunk * 9216;
    const int n4 = M * 256 / 4;
    hipLaunchKernelGGL(k_cvt, dim3((n4 + 255)/256), dim3(256), 0, stream, (const float4*)xc, (ushort4*)xb, n4);
    hipLaunchKernelGGL(k_gemm, dim3(M/128, 6), dim3(256), 0, stream,
                       xb, wqb, qkvb, (float*)nullptr, (const float*)nullptr, (const float*)nullptr, M, 768, 256);
    hipLaunchKernelGGL(k_kstats, dim3(8, chunk), dim3(256), 0, stream, qkvb, kmaxb, kizb);
    hipLaunchKernelGGL(k_ctx, dim3(8, chunk, 4), dim3(256), 0, stream, qkvb, kmaxb, kizb, ctxpb);
    hipLaunchKernelGGL(k_ctxred, dim3(chunk), dim3(256), 0, stream, ctxpb, ctxb);
    hipLaunchKernelGGL(k_attn, dim3(256, chunk), dim3(256), 0, stream, qkvb, ctxb, Ab);
    hipLaunchKernelGGL(k_gemm, dim3(M/128, 2), dim3(256), 0, stream,
                       Ab, wc, (u16*)nullptr, oc, bc, xc, M, 256, 256);
  }
}

// Round 2
// 372.058 us; speedup vs baseline: 3.2434x; 3.2434x over previous
//
#include <hip/hip_runtime.h>

using u16 = unsigned short;
typedef __attribute__((ext_vector_type(8))) short short8;
typedef __attribute__((ext_vector_type(4))) float f32x4;

__device__ __forceinline__ float b2f(u16 u){ union{unsigned u; float f;} c; c.u = ((unsigned)u) << 16; return c.f; }
__device__ __forceinline__ u16 f2b(float f){
  union{float f; unsigned u;} c; c.f = f;
  unsigned r = 0x7fffu + ((c.u >> 16) & 1u);
  return (u16)((c.u + r) >> 16);
}
__device__ __forceinline__ float lo2f(unsigned u){ union{unsigned u; float f;} c; c.u = u << 16; return c.f; }
__device__ __forceinline__ float hi2f(unsigned u){ union{unsigned u; float f;} c; c.u = u & 0xffff0000u; return c.f; }

#define GLOAD_LDS16(g, l) __builtin_amdgcn_global_load_lds( \
  (const __attribute__((address_space(1))) unsigned int*)(g), \
  (__attribute__((address_space(3))) unsigned int*)(l), 16, 0, 0)

// ---------- f32 -> bf16 convert, 4/thread ----------
__global__ void k_cvt(const float4* __restrict__ in, ushort4* __restrict__ out, int n4){
  int i = blockIdx.x * 256 + threadIdx.x;
  if (i < n4){
    float4 v = in[i];
    ushort4 o; o.x = f2b(v.x); o.y = f2b(v.y); o.z = f2b(v.z); o.w = f2b(v.w);
    out[i] = o;
  }
}

// ---------- W_comb = w_lin @ w_out (bf16), b_comb = w_lin@b_out + b_lin ----------
__global__ __launch_bounds__(256) void k_prepw(const float* __restrict__ w_lin, const float* __restrict__ w_out,
    const float* __restrict__ b_out, const float* __restrict__ b_lin,
    u16* __restrict__ wc, float* __restrict__ bc){
  int l = blockIdx.x, i = threadIdx.x;
  float s = 0.f;
  for (int j = 0; j < 256; ++j) s += w_lin[l*256 + j] * w_out[j*256 + i];
  wc[l*256 + i] = f2b(s);
  __shared__ float red[256];
  red[i] = w_lin[l*256 + i] * b_out[i];
  __syncthreads();
  for (int off = 128; off > 0; off >>= 1){ if (i < off) red[i] += red[i + off]; __syncthreads(); }
  if (i == 0) bc[l] = red[0] + b_lin[l];
}

// ---------- MFMA bf16 GEMM: C[M,N] = A[M,K] @ B[N,K]^T ----------
// 128x128 tile, BK=32, 4 waves, 4x4 16x16x32 fragments per wave.
// LDS chunk-XOR swizzle; global source pre-swizzled to match (linear global_load_lds dest).
__global__ __launch_bounds__(256) void k_gemm_mfma(const u16* __restrict__ A, const u16* __restrict__ B,
    u16* __restrict__ Cb, float* __restrict__ Cf,
    const float* __restrict__ bias, const float* __restrict__ resid,
    int M, int N, int K){
  __shared__ __align__(16) u16 As[128*32];
  __shared__ __align__(16) u16 Bs[128*32];
  const int t = threadIdx.x;
  const int wave = t >> 6, lane = t & 63;
  const int bm = blockIdx.x * 128, bn = blockIdx.y * 128;
  // staging: issue (wave,i) covers tile rows wave*32+i*16 .. +15; lane -> row + (lane>>2), chunk lane&3
  const int srow = wave*32 + (lane>>2);
  const int skel = (((lane&3) ^ ((lane>>2)&3)) << 3);   // pre-swizzled k chunk
  const u16* ag = A + (size_t)(bm + srow)*K + skel;
  const u16* bg = B + (size_t)(bn + srow)*K + skel;
  u16* asl = As + wave*1024;   // wave-uniform LDS dest (elems); +512 for second 16 rows
  u16* bsl = Bs + wave*1024;
  const size_t rstep = (size_t)16*K;
  // fragment geometry
  const int wr = (wave>>1)*64, wc4 = (wave&1)*64;
  const int fr = lane & 15;
  const int fkc = lane >> 4;                       // logical k chunk 0..3
  const int koff = ((fkc ^ (fr&3)) << 3);          // swizzled phys chunk -> elem offset
  f32x4 acc[4][4] = {};
  for (int k0 = 0; k0 < K; k0 += 32){
    GLOAD_LDS16(ag + k0,         asl);
    GLOAD_LDS16(ag + rstep + k0, asl + 512);
    GLOAD_LDS16(bg + k0,         bsl);
    GLOAD_LDS16(bg + rstep + k0, bsl + 512);
    __syncthreads();
    short8 av[4], bv[4];
    #pragma unroll
    for (int m = 0; m < 4; ++m)
      av[m] = *(const short8*)&As[(wr + m*16 + fr)*32 + koff];
    #pragma unroll
    for (int n = 0; n < 4; ++n)
      bv[n] = *(const short8*)&Bs[(wc4 + n*16 + fr)*32 + koff];
    #pragma unroll
    for (int m = 0; m < 4; ++m)
      #pragma unroll
      for (int n = 0; n < 4; ++n)
        acc[m][n] = __builtin_amdgcn_mfma_f32_16x16x32_bf16(av[m], bv[n], acc[m][n], 0, 0, 0);
    __syncthreads();
  }
  const int orow0 = bm + wr + (lane>>4)*4;
  const int ocol0 = bn + wc4 + fr;
  if (Cf){
    #pragma unroll
    for (int m = 0; m < 4; ++m)
      #pragma unroll
      for (int r = 0; r < 4; ++r){
        size_t base = (size_t)(orow0 + m*16 + r) * N;
        #pragma unroll
        for (int n = 0; n < 4; ++n){
          int col = ocol0 + n*16;
          Cf[base + col] = acc[m][n][r] + bias[col] + resid[base + col];
        }
      }
  } else {
    #pragma unroll
    for (int m = 0; m < 4; ++m)
      #pragma unroll
      for (int r = 0; r < 4; ++r){
        size_t base = (size_t)(orow0 + m*16 + r) * N;
        #pragma unroll
        for (int n = 0; n < 4; ++n)
          Cb[base + ocol0 + n*16] = f2b(acc[m][n][r]);
      }
  }
}

// ---------- k softmax stats, pass 1: per-split online (max,sumexp) per channel ----------
// grid (72, nf); thread t = channel t; 128 tokens per split, coalesced 512B rows
__global__ __launch_bounds__(256) void k_kstats1(const u16* __restrict__ qkv,
    float* __restrict__ pm, float* __restrict__ ps){
  const int s = blockIdx.x, frel = blockIdx.y, c = threadIdx.x;
  const u16* base = qkv + (size_t)frel*9216*768 + (size_t)s*128*768 + 256 + c;
  float m0 = -1e30f, s0 = 0.f, m1 = -1e30f, s1 = 0.f;
  #pragma unroll 4
  for (int n = 0; n < 64; ++n){
    float v0 = b2f(base[(size_t)n*768]);
    float v1 = b2f(base[(size_t)(n+64)*768]);
    float nm0 = fmaxf(m0, v0); s0 = s0*__expf(m0-nm0) + __expf(v0-nm0); m0 = nm0;
    float nm1 = fmaxf(m1, v1); s1 = s1*__expf(m1-nm1) + __expf(v1-nm1); m1 = nm1;
  }
  float m = fmaxf(m0, m1);
  float sum = s0*__expf(m0-m) + s1*__expf(m1-m);
  size_t idx = ((size_t)frel*72 + s)*256 + c;
  pm[idx] = m; ps[idx] = sum;
}

// ---------- k softmax stats, pass 2: reduce 72 splits ----------
__global__ __launch_bounds__(256) void k_kstats2(const float* __restrict__ pm, const float* __restrict__ ps,
    float* __restrict__ kmax, float* __restrict__ kiz){
  int frel = blockIdx.x, c = threadIdx.x;
  size_t b = (size_t)frel*72*256 + c;
  float m = -1e30f;
  #pragma unroll 8
  for (int s = 0; s < 72; ++s) m = fmaxf(m, pm[b + s*256]);
  float sum = 0.f;
  #pragma unroll 8
  for (int s = 0; s < 72; ++s) sum += ps[b + s*256] * __expf(pm[b + s*256] - m);
  kmax[frel*256 + c] = m;
  kiz [frel*256 + c] = 1.0f/sum;
}

// ---------- ctx partials: ctx[dd,e] += softmax_k[dd,n] * v[e,n] ----------
// grid (H=8, nf, S=16); each block does 576 tokens
__global__ __launch_bounds__(256) void k_ctx(const u16* __restrict__ qkv,
    const float* __restrict__ kmax, const float* __restrict__ kiz, float* __restrict__ ctxp){
  const int h = blockIdx.x, frel = blockIdx.y, s = blockIdx.z;
  const int t = threadIdx.x;
  const int lc = t & 31, lrow = t >> 5;
  const int e4 = (t & 7) * 4, dd = t >> 3;
  __shared__ float Ks[64][32];
  __shared__ float Vs[64][32];
  const u16* kb = qkv + (size_t)frel * 9216 * 768 + 256 + h * 32;
  const u16* vb = kb + 256;
  const float mx = kmax[frel*256 + h*32 + lc];
  const float iz = kiz [frel*256 + h*32 + lc];
  float acc0=0.f, acc1=0.f, acc2=0.f, acc3=0.f;
  const int nend = (s + 1) * 576;
  for (int n0 = s * 576; n0 < nend; n0 += 64){
    __syncthreads();
    #pragma unroll
    for (int ii = 0; ii < 8; ++ii){
      int nl = lrow + 8*ii;
      size_t off = (size_t)(n0 + nl) * 768;
      Ks[nl][lc] = __expf(b2f(kb[off + lc]) - mx) * iz;
      Vs[nl][lc] = b2f(vb[off + lc]);
    }
    __syncthreads();
    #pragma unroll
    for (int nn = 0; nn < 64; ++nn){
      float p = Ks[nn][dd];
      float4 v = *(const float4*)&Vs[nn][e4];
      acc0 += p*v.x; acc1 += p*v.y; acc2 += p*v.z; acc3 += p*v.w;
    }
  }
  float* cb = ctxp + (((size_t)frel*16 + s)*8 + h)*1024 + dd*32 + e4;
  cb[0]=acc0; cb[1]=acc1; cb[2]=acc2; cb[3]=acc3;
}

__global__ void k_ctxred(const float* __restrict__ ctxp, float* __restrict__ ctx){
  int frel = blockIdx.x, t = threadIdx.x;
  for (int i = t; i < 8192; i += 256){
    float s = 0.f;
    #pragma unroll
    for (int q = 0; q < 16; ++q) s += ctxp[((size_t)frel*16 + q)*8192 + i];
    ctx[(size_t)frel*8192 + i] = s;
  }
}

// ---------- per-token: q channel-softmax*scale, A = ctx^T applied ----------
__global__ __launch_bounds__(256) void k_attn(const u16* __restrict__ qkv,
    const float* __restrict__ ctx, u16* __restrict__ Ab){
  const int frel = blockIdx.y;
  const int tb = blockIdx.x * 36;
  const int t = threadIdx.x;
  const int lane = t & 63;
  const int c = t, h = c >> 5, e = c & 31;
  __shared__ float cs[8192];
  for (int i = t; i < 8192; i += 256) cs[i] = ctx[(size_t)frel*8192 + i];
  __syncthreads();
  const float scale = 0.17677669529663689f;
  const float* ch = &cs[h*1024 + e];
  for (int tk = 0; tk < 36; ++tk){
    size_t tok = (size_t)frel * 9216 + tb + tk;
    float q = b2f(qkv[tok * 768 + c]);
    float m = q;
    #pragma unroll
    for (int off = 16; off > 0; off >>= 1) m = fmaxf(m, __shfl_xor(m, off, 64));
    float p = __expf(q - m);
    float s = p;
    #pragma unroll
    for (int off = 16; off > 0; off >>= 1) s += __shfl_xor(s, off, 64);
    float qsm = p / s * scale;
    float acc = 0.f;
    #pragma unroll
    for (int dd = 0; dd < 32; ++dd){
      float qv = __shfl(qsm, (lane & 32) + dd, 64);
      acc += qv * ch[dd * 32];
    }
    Ab[tok * 256 + c] = f2b(acc);
  }
}

extern "C" void kernel_launch(void* const* d_in, const int* in_sizes, int n_in,
                              void* d_out, int out_size, void* d_ws, size_t ws_size,
                              hipStream_t stream){
  const float* x     = (const float*)d_in[0];
  const float* w_qkv = (const float*)d_in[1];
  const float* w_out = (const float*)d_in[2];
  const float* b_out = (const float*)d_in[3];
  const float* w_lin = (const float*)d_in[4];
  const float* b_lin = (const float*)d_in[5];
  float* out = (float*)d_out;

  char* p = (char*)d_ws;
  u16*   wqb   = (u16*)p;   p += (size_t)768*256*2;
  u16*   wcb   = (u16*)p;   p += (size_t)256*256*2;
  float* bc    = (float*)p; p += 256*4;
  float* kmaxb = (float*)p; p += 8*256*4;
  float* kizb  = (float*)p; p += 8*256*4;
  float* pmb   = (float*)p; p += (size_t)8*72*256*4;
  float* psb   = (float*)p; p += (size_t)8*72*256*4;
  float* ctxpb = (float*)p; p += (size_t)8*16*8192*4;
  float* ctxb  = (float*)p; p += (size_t)8*8192*4;
  size_t fixed = (size_t)(p - (char*)d_ws);
  size_t per_frame = (size_t)9216*256*2 + (size_t)9216*768*2 + (size_t)9216*256*2;
  int chunk = (ws_size >= fixed + 8*per_frame) ? 8 : 1;
  u16* xb   = (u16*)p;
  u16* qkvb = xb   + (size_t)chunk*9216*256;
  u16* Ab   = qkvb + (size_t)chunk*9216*768;

  // weight prep (once)
  hipLaunchKernelGGL(k_cvt, dim3(192), dim3(256), 0, stream, (const float4*)w_qkv, (ushort4*)wqb, 49152);
  hipLaunchKernelGGL(k_prepw, dim3(256), dim3(256), 0, stream, w_lin, w_out, b_out, b_lin, wcb, bc);

  for (int f0 = 0; f0 < 8; f0 += chunk){
    const float* xc = x  + (size_t)f0*9216*256;
    float*       oc = out + (size_t)f0*9216*256;
    const int M = chunk * 9216;
    const int n4 = M * 256 / 4;
    hipLaunchKernelGGL(k_cvt, dim3((n4 + 255)/256), dim3(256), 0, stream, (const float4*)xc, (ushort4*)xb, n4);
    hipLaunchKernelGGL(k_gemm_mfma, dim3(M/128, 6), dim3(256), 0, stream,
                       xb, wqb, qkvb, (float*)nullptr, (const float*)nullptr, (const float*)nullptr, M, 768, 256);
    hipLaunchKernelGGL(k_kstats1, dim3(72, chunk), dim3(256), 0, stream, qkvb, pmb, psb);
    hipLaunchKernelGGL(k_kstats2, dim3(chunk), dim3(256), 0, stream, pmb, psb, kmaxb, kizb);
    hipLaunchKernelGGL(k_ctx, dim3(8, chunk, 16), dim3(256), 0, stream, qkvb, kmaxb, kizb, ctxpb);
    hipLaunchKernelGGL(k_ctxred, dim3(chunk), dim3(256), 0, stream, ctxpb, ctxb);
    hipLaunchKernelGGL(k_attn, dim3(256, chunk), dim3(256), 0, stream, qkvb, ctxb, Ab);
    hipLaunchKernelGGL(k_gemm_mfma, dim3(M/128, 2), dim3(256), 0, stream,
                       Ab, wcb, (u16*)nullptr, oc, bc, xc, M, 256, 256);
  }
}

// Round 3
// 267.597 us; speedup vs baseline: 4.5096x; 1.3904x over previous
//
#include <hip/hip_runtime.h>

using u16 = unsigned short;
typedef __attribute__((ext_vector_type(8))) short short8;
typedef __attribute__((ext_vector_type(4))) float f32x4;

__device__ __forceinline__ float b2f(u16 u){ union{unsigned u; float f;} c; c.u = ((unsigned)u) << 16; return c.f; }
__device__ __forceinline__ u16 f2b(float f){
  union{float f; unsigned u;} c; c.f = f;
  unsigned r = 0x7fffu + ((c.u >> 16) & 1u);
  return (u16)((c.u + r) >> 16);
}

#define GLOAD_LDS16(g, l) __builtin_amdgcn_global_load_lds( \
  (const __attribute__((address_space(1))) unsigned int*)(g), \
  (__attribute__((address_space(3))) unsigned int*)(l), 16, 0, 0)

// ---------- f32 -> bf16 convert, 4/thread ----------
__global__ void k_cvt(const float4* __restrict__ in, ushort4* __restrict__ out, int n4){
  int i = blockIdx.x * 256 + threadIdx.x;
  if (i < n4){
    float4 v = in[i];
    ushort4 o; o.x = f2b(v.x); o.y = f2b(v.y); o.z = f2b(v.z); o.w = f2b(v.w);
    out[i] = o;
  }
}

// ---------- Wcomb = w_lin @ w_out (fp32), b_comb = w_lin@b_out + b_lin ----------
__global__ __launch_bounds__(256) void k_prepw(const float* __restrict__ w_lin, const float* __restrict__ w_out,
    const float* __restrict__ b_out, const float* __restrict__ b_lin,
    float* __restrict__ wcf, float* __restrict__ bc){
  int l = blockIdx.x, i = threadIdx.x;
  float s = 0.f;
  for (int j = 0; j < 256; ++j) s += w_lin[l*256 + j] * w_out[j*256 + i];
  wcf[l*256 + i] = s;
  __shared__ float red[256];
  red[i] = w_lin[l*256 + i] * b_out[i];
  __syncthreads();
  for (int off = 128; off > 0; off >>= 1){ if (i < off) red[i] += red[i + off]; __syncthreads(); }
  if (i == 0) bc[l] = red[0] + b_lin[l];
}

// ---------- MFMA bf16 GEMM: C[M,N] = A[M,K] @ B[N,K]^T ----------
// 128x128 tile, BK=32, 4 waves, 4x4 16x16x32 fragments per wave.
// frame_rows>0: B is per-frame, block uses B + (bm/frame_rows)*N*K.
__global__ __launch_bounds__(256) void k_gemm_mfma(const u16* __restrict__ A, const u16* __restrict__ B,
    u16* __restrict__ Cb, float* __restrict__ Cf,
    const float* __restrict__ bias, const float* __restrict__ resid,
    int M, int N, int K, int frame_rows){
  __shared__ __align__(16) u16 As[128*32];
  __shared__ __align__(16) u16 Bs[128*32];
  const int t = threadIdx.x;
  const int wave = t >> 6, lane = t & 63;
  const int bm = blockIdx.x * 128, bn = blockIdx.y * 128;
  if (frame_rows > 0) B += (size_t)(bm / frame_rows) * N * K;
  const int srow = wave*32 + (lane>>2);
  const int skel = (((lane&3) ^ ((lane>>2)&3)) << 3);   // pre-swizzled k chunk
  const u16* ag = A + (size_t)(bm + srow)*K + skel;
  const u16* bg = B + (size_t)(bn + srow)*K + skel;
  u16* asl = As + wave*1024;
  u16* bsl = Bs + wave*1024;
  const size_t rstep = (size_t)16*K;
  const int wr = (wave>>1)*64, wc4 = (wave&1)*64;
  const int fr = lane & 15;
  const int fkc = lane >> 4;
  const int koff = ((fkc ^ (fr&3)) << 3);
  f32x4 acc[4][4] = {};
  for (int k0 = 0; k0 < K; k0 += 32){
    GLOAD_LDS16(ag + k0,         asl);
    GLOAD_LDS16(ag + rstep + k0, asl + 512);
    GLOAD_LDS16(bg + k0,         bsl);
    GLOAD_LDS16(bg + rstep + k0, bsl + 512);
    __syncthreads();
    short8 av[4], bv[4];
    #pragma unroll
    for (int m = 0; m < 4; ++m)
      av[m] = *(const short8*)&As[(wr + m*16 + fr)*32 + koff];
    #pragma unroll
    for (int n = 0; n < 4; ++n)
      bv[n] = *(const short8*)&Bs[(wc4 + n*16 + fr)*32 + koff];
    #pragma unroll
    for (int m = 0; m < 4; ++m)
      #pragma unroll
      for (int n = 0; n < 4; ++n)
        acc[m][n] = __builtin_amdgcn_mfma_f32_16x16x32_bf16(av[m], bv[n], acc[m][n], 0, 0, 0);
    __syncthreads();
  }
  const int orow0 = bm + wr + (lane>>4)*4;
  const int ocol0 = bn + wc4 + fr;
  if (Cf){
    #pragma unroll
    for (int m = 0; m < 4; ++m)
      #pragma unroll
      for (int r = 0; r < 4; ++r){
        size_t base = (size_t)(orow0 + m*16 + r) * N;
        #pragma unroll
        for (int n = 0; n < 4; ++n){
          int col = ocol0 + n*16;
          Cf[base + col] = acc[m][n][r] + bias[col] + resid[base + col];
        }
      }
  } else {
    #pragma unroll
    for (int m = 0; m < 4; ++m)
      #pragma unroll
      for (int r = 0; r < 4; ++r){
        size_t base = (size_t)(orow0 + m*16 + r) * N;
        #pragma unroll
        for (int n = 0; n < 4; ++n)
          Cb[base + ocol0 + n*16] = f2b(acc[m][n][r]);
      }
  }
}

// ---------- k softmax stats, pass 1 ----------
__global__ __launch_bounds__(256) void k_kstats1(const u16* __restrict__ qkv,
    float* __restrict__ pm, float* __restrict__ ps){
  const int s = blockIdx.x, frel = blockIdx.y, c = threadIdx.x;
  const u16* base = qkv + (size_t)frel*9216*768 + (size_t)s*128*768 + 256 + c;
  float m0 = -1e30f, s0 = 0.f, m1 = -1e30f, s1 = 0.f;
  #pragma unroll 4
  for (int n = 0; n < 64; ++n){
    float v0 = b2f(base[(size_t)n*768]);
    float v1 = b2f(base[(size_t)(n+64)*768]);
    float nm0 = fmaxf(m0, v0); s0 = s0*__expf(m0-nm0) + __expf(v0-nm0); m0 = nm0;
    float nm1 = fmaxf(m1, v1); s1 = s1*__expf(m1-nm1) + __expf(v1-nm1); m1 = nm1;
  }
  float m = fmaxf(m0, m1);
  float sum = s0*__expf(m0-m) + s1*__expf(m1-m);
  size_t idx = ((size_t)frel*72 + s)*256 + c;
  pm[idx] = m; ps[idx] = sum;
}

// ---------- k softmax stats, pass 2 ----------
__global__ __launch_bounds__(256) void k_kstats2(const float* __restrict__ pm, const float* __restrict__ ps,
    float* __restrict__ kmax, float* __restrict__ kiz){
  int frel = blockIdx.x, c = threadIdx.x;
  size_t b = (size_t)frel*72*256 + c;
  float m = -1e30f;
  #pragma unroll 8
  for (int s = 0; s < 72; ++s) m = fmaxf(m, pm[b + s*256]);
  float sum = 0.f;
  #pragma unroll 8
  for (int s = 0; s < 72; ++s) sum += ps[b + s*256] * __expf(pm[b + s*256] - m);
  kmax[frel*256 + c] = m;
  kiz [frel*256 + c] = 1.0f/sum;
}

// ---------- ctx partials: ctx[dd,e] += softmax_k[dd,n] * v[e,n] ----------
__global__ __launch_bounds__(256) void k_ctx(const u16* __restrict__ qkv,
    const float* __restrict__ kmax, const float* __restrict__ kiz, float* __restrict__ ctxp){
  const int h = blockIdx.x, frel = blockIdx.y, s = blockIdx.z;
  const int t = threadIdx.x;
  const int lc = t & 31, lrow = t >> 5;
  const int e4 = (t & 7) * 4, dd = t >> 3;
  __shared__ float Ks[64][32];
  __shared__ float Vs[64][32];
  const u16* kb = qkv + (size_t)frel * 9216 * 768 + 256 + h * 32;
  const u16* vb = kb + 256;
  const float mx = kmax[frel*256 + h*32 + lc];
  const float iz = kiz [frel*256 + h*32 + lc];
  float acc0=0.f, acc1=0.f, acc2=0.f, acc3=0.f;
  const int nend = (s + 1) * 576;
  for (int n0 = s * 576; n0 < nend; n0 += 64){
    __syncthreads();
    #pragma unroll
    for (int ii = 0; ii < 8; ++ii){
      int nl = lrow + 8*ii;
      size_t off = (size_t)(n0 + nl) * 768;
      Ks[nl][lc] = __expf(b2f(kb[off + lc]) - mx) * iz;
      Vs[nl][lc] = b2f(vb[off + lc]);
    }
    __syncthreads();
    #pragma unroll
    for (int nn = 0; nn < 64; ++nn){
      float p = Ks[nn][dd];
      float4 v = *(const float4*)&Vs[nn][e4];
      acc0 += p*v.x; acc1 += p*v.y; acc2 += p*v.z; acc3 += p*v.w;
    }
  }
  float* cb = ctxp + (((size_t)frel*16 + s)*8 + h)*1024 + dd*32 + e4;
  cb[0]=acc0; cb[1]=acc1; cb[2]=acc2; cb[3]=acc3;
}

__global__ void k_ctxred(const float* __restrict__ ctxp, float* __restrict__ ctx){
  int frel = blockIdx.x, t = threadIdx.x;
  for (int i = t; i < 8192; i += 256){
    float s = 0.f;
    #pragma unroll
    for (int q = 0; q < 16; ++q) s += ctxp[((size_t)frel*16 + q)*8192 + i];
    ctx[(size_t)frel*8192 + i] = s;
  }
}

// ---------- per-(token,head) q channel-softmax * scale -> bf16 ----------
// thread g: tok = g>>3, head = g&7; 32 contiguous channels, no shuffles.
__global__ __launch_bounds__(256) void k_qsm(const u16* __restrict__ qkv, u16* __restrict__ qs, int ntok){
  int g = blockIdx.x * 256 + threadIdx.x;
  int tok = g >> 3, h = g & 7;
  if (tok >= ntok) return;
  const u16* src = qkv + (size_t)tok*768 + h*32;
  short8 v[4];
  #pragma unroll
  for (int i = 0; i < 4; ++i) v[i] = *(const short8*)(src + i*8);
  float f[32];
  #pragma unroll
  for (int i = 0; i < 4; ++i)
    #pragma unroll
    for (int j = 0; j < 8; ++j) f[i*8+j] = b2f((u16)v[i][j]);
  float m = f[0];
  #pragma unroll
  for (int i = 1; i < 32; ++i) m = fmaxf(m, f[i]);
  float s = 0.f;
  #pragma unroll
  for (int i = 0; i < 32; ++i){ float p = __expf(f[i] - m); f[i] = p; s += p; }
  float r = 0.17677669529663689f / s;
  u16* dst = qs + (size_t)tok*256 + h*32;
  #pragma unroll
  for (int i = 0; i < 4; ++i){
    short8 o;
    #pragma unroll
    for (int j = 0; j < 8; ++j) o[j] = (short)f2b(f[i*8+j] * r);
    *(short8*)(dst + i*8) = o;
  }
}

// ---------- Weff_f[l, h*32+dd] = sum_e ctx_f[h][dd,e] * Wcomb[l, h*32+e] ----------
// grid (256 l, nf); thread t = h*32+dd
__global__ __launch_bounds__(256) void k_weff(const float* __restrict__ ctx, const float* __restrict__ wcf,
    u16* __restrict__ weff){
  int l = blockIdx.x, frel = blockIdx.y, t = threadIdx.x;
  int h = t >> 5, dd = t & 31;
  const float* cr = ctx + (size_t)frel*8192 + h*1024 + dd*32;
  const float* wr = wcf + (size_t)l*256 + h*32;
  float s = 0.f;
  #pragma unroll
  for (int e = 0; e < 32; ++e) s += cr[e] * wr[e];
  weff[((size_t)frel*256 + l)*256 + t] = f2b(s);
}

extern "C" void kernel_launch(void* const* d_in, const int* in_sizes, int n_in,
                              void* d_out, int out_size, void* d_ws, size_t ws_size,
                              hipStream_t stream){
  const float* x     = (const float*)d_in[0];
  const float* w_qkv = (const float*)d_in[1];
  const float* w_out = (const float*)d_in[2];
  const float* b_out = (const float*)d_in[3];
  const float* w_lin = (const float*)d_in[4];
  const float* b_lin = (const float*)d_in[5];
  float* out = (float*)d_out;

  char* p = (char*)d_ws;
  u16*   wqb   = (u16*)p;   p += (size_t)768*256*2;
  float* wcf   = (float*)p; p += (size_t)256*256*4;
  float* bc    = (float*)p; p += 256*4;
  float* kmaxb = (float*)p; p += 8*256*4;
  float* kizb  = (float*)p; p += 8*256*4;
  float* pmb   = (float*)p; p += (size_t)8*72*256*4;
  float* psb   = (float*)p; p += (size_t)8*72*256*4;
  float* ctxpb = (float*)p; p += (size_t)8*16*8192*4;
  float* ctxb  = (float*)p; p += (size_t)8*8192*4;
  u16*   weffb = (u16*)p;   p += (size_t)8*256*256*2;
  size_t fixed = (size_t)(p - (char*)d_ws);
  size_t per_frame = (size_t)9216*256*2 + (size_t)9216*768*2 + (size_t)9216*256*2;
  int chunk = (ws_size >= fixed + 8*per_frame) ? 8 : 1;
  u16* xb   = (u16*)p;
  u16* qkvb = xb   + (size_t)chunk*9216*256;
  u16* qsmb = qkvb + (size_t)chunk*9216*768;

  // weight prep (once)
  hipLaunchKernelGGL(k_cvt, dim3(192), dim3(256), 0, stream, (const float4*)w_qkv, (ushort4*)wqb, 49152);
  hipLaunchKernelGGL(k_prepw, dim3(256), dim3(256), 0, stream, w_lin, w_out, b_out, b_lin, wcf, bc);

  for (int f0 = 0; f0 < 8; f0 += chunk){
    const float* xc = x  + (size_t)f0*9216*256;
    float*       oc = out + (size_t)f0*9216*256;
    const int M = chunk * 9216;
    const int n4 = M * 256 / 4;
    hipLaunchKernelGGL(k_cvt, dim3((n4 + 255)/256), dim3(256), 0, stream, (const float4*)xc, (ushort4*)xb, n4);
    hipLaunchKernelGGL(k_gemm_mfma, dim3(M/128, 6), dim3(256), 0, stream,
                       xb, wqb, qkvb, (float*)nullptr, (const float*)nullptr, (const float*)nullptr,
                       M, 768, 256, 0);
    hipLaunchKernelGGL(k_kstats1, dim3(72, chunk), dim3(256), 0, stream, qkvb, pmb, psb);
    hipLaunchKernelGGL(k_kstats2, dim3(chunk), dim3(256), 0, stream, pmb, psb, kmaxb, kizb);
    hipLaunchKernelGGL(k_ctx, dim3(8, chunk, 16), dim3(256), 0, stream, qkvb, kmaxb, kizb, ctxpb);
    hipLaunchKernelGGL(k_ctxred, dim3(chunk), dim3(256), 0, stream, ctxpb, ctxb);
    hipLaunchKernelGGL(k_qsm, dim3(M*8/256, 1), dim3(256), 0, stream, qkvb, qsmb, M);
    hipLaunchKernelGGL(k_weff, dim3(256, chunk), dim3(256), 0, stream,
                       ctxb, wcf, weffb + (size_t)f0*256*256);
    hipLaunchKernelGGL(k_gemm_mfma, dim3(M/128, 2), dim3(256), 0, stream,
                       qsmb, weffb + (size_t)f0*256*256, (u16*)nullptr, oc, bc, xc,
                       M, 256, 256, (chunk == 8) ? 9216 : 0);
  }
}

// Round 5
// 257.370 us; speedup vs baseline: 4.6888x; 1.0397x over previous
//
#include <hip/hip_runtime.h>

using u16 = unsigned short;
typedef __attribute__((ext_vector_type(8))) short short8;
typedef __attribute__((ext_vector_type(4))) float f32x4;

__device__ __forceinline__ float b2f(u16 u){ union{unsigned u; float f;} c; c.u = ((unsigned)u) << 16; return c.f; }
__device__ __forceinline__ u16 f2b(float f){
  union{float f; unsigned u;} c; c.f = f;
  unsigned r = 0x7fffu + ((c.u >> 16) & 1u);
  return (u16)((c.u + r) >> 16);
}

#define GLOAD_LDS16(g, l) __builtin_amdgcn_global_load_lds( \
  (const __attribute__((address_space(1))) unsigned int*)(g), \
  (__attribute__((address_space(3))) unsigned int*)(l), 16, 0, 0)

// ---------- f32 -> bf16 convert, 4/thread ----------
__global__ void k_cvt(const float4* __restrict__ in, ushort4* __restrict__ out, int n4){
  int i = blockIdx.x * 256 + threadIdx.x;
  if (i < n4){
    float4 v = in[i];
    ushort4 o; o.x = f2b(v.x); o.y = f2b(v.y); o.z = f2b(v.z); o.w = f2b(v.w);
    out[i] = o;
  }
}

// ---------- Wcomb = w_lin @ w_out (fp32), b_comb = w_lin@b_out + b_lin ----------
__global__ __launch_bounds__(256) void k_prepw(const float* __restrict__ w_lin, const float* __restrict__ w_out,
    const float* __restrict__ b_out, const float* __restrict__ b_lin,
    float* __restrict__ wcf, float* __restrict__ bc){
  int l = blockIdx.x, i = threadIdx.x;
  float s = 0.f;
  for (int j = 0; j < 256; ++j) s += w_lin[l*256 + j] * w_out[j*256 + i];
  wcf[l*256 + i] = s;
  __shared__ float red[256];
  red[i] = w_lin[l*256 + i] * b_out[i];
  __syncthreads();
  for (int off = 128; off > 0; off >>= 1){ if (i < off) red[i] += red[i + off]; __syncthreads(); }
  if (i == 0) bc[l] = red[0] + b_lin[l];
}

// ---------- MFMA bf16 GEMM: C[M,N] = A[M,K] @ B[N,K]^T ----------
// 128x128 tile, BK=32, 4 waves, 4x4 16x16x32 fragments.
// Double-buffered LDS, counted vmcnt(4), raw barriers (T3/T4 2-phase).
// Swizzle: phys chunk = logical ^ ((row>>1)&3), inverse pre-applied to global src.
template<int K>
__global__ __launch_bounds__(256) void k_gemm_mfma(const u16* __restrict__ A, const u16* __restrict__ B,
    u16* __restrict__ Cb, float* __restrict__ Cf,
    const float* __restrict__ bias, const float* __restrict__ resid,
    int M, int N, int frame_rows){
  __shared__ __align__(16) u16 As[2][128*32];
  __shared__ __align__(16) u16 Bs[2][128*32];
  const int t = threadIdx.x;
  const int wave = t >> 6, lane = t & 63;
  const int bm = blockIdx.x * 128, bn = blockIdx.y * 128;
  if (frame_rows > 0) B += (size_t)(bm / frame_rows) * N * K;
  const int srow = wave*32 + (lane>>2);
  const int skel = (((lane&3) ^ ((lane>>3)&3)) << 3);   // inverse-swizzled global k chunk
  const u16* ag = A + (size_t)(bm + srow)*K + skel;
  const u16* bg = B + (size_t)(bn + srow)*K + skel;
  const size_t rstep = (size_t)16*K;
  const int wr = (wave>>1)*64, wc4 = (wave&1)*64;
  const int fr = lane & 15;
  const int fkc = lane >> 4;
  const int koff = ((fkc ^ ((fr>>1)&3)) << 3);          // swizzled phys chunk on read
  f32x4 acc[4][4] = {};
  {
    u16* asl = As[0] + wave*1024; u16* bsl = Bs[0] + wave*1024;
    GLOAD_LDS16(ag,         asl);
    GLOAD_LDS16(ag + rstep, asl + 512);
    GLOAD_LDS16(bg,         bsl);
    GLOAD_LDS16(bg + rstep, bsl + 512);
  }
  #pragma unroll
  for (int it = 0; it < K/32; ++it){
    const int cur = it & 1;
    if (it + 1 < K/32){
      u16* asl = As[cur^1] + wave*1024; u16* bsl = Bs[cur^1] + wave*1024;
      const int k0 = (it+1)*32;
      GLOAD_LDS16(ag + k0,         asl);
      GLOAD_LDS16(ag + rstep + k0, asl + 512);
      GLOAD_LDS16(bg + k0,         bsl);
      GLOAD_LDS16(bg + rstep + k0, bsl + 512);
      asm volatile("s_waitcnt vmcnt(4)" ::: "memory");
    } else {
      asm volatile("s_waitcnt vmcnt(0)" ::: "memory");
    }
    __builtin_amdgcn_s_barrier();
    short8 av[4], bv[4];
    #pragma unroll
    for (int m = 0; m < 4; ++m)
      av[m] = *(const short8*)&As[cur][(wr + m*16 + fr)*32 + koff];
    #pragma unroll
    for (int n = 0; n < 4; ++n)
      bv[n] = *(const short8*)&Bs[cur][(wc4 + n*16 + fr)*32 + koff];
    #pragma unroll
    for (int m = 0; m < 4; ++m)
      #pragma unroll
      for (int n = 0; n < 4; ++n)
        acc[m][n] = __builtin_amdgcn_mfma_f32_16x16x32_bf16(av[m], bv[n], acc[m][n], 0, 0, 0);
    __builtin_amdgcn_s_barrier();
  }
  const int orow0 = bm + wr + (lane>>4)*4;
  const int ocol0 = bn + wc4 + fr;
  if (Cf){
    #pragma unroll
    for (int m = 0; m < 4; ++m)
      #pragma unroll
      for (int r = 0; r < 4; ++r){
        size_t base = (size_t)(orow0 + m*16 + r) * N;
        #pragma unroll
        for (int n = 0; n < 4; ++n){
          int col = ocol0 + n*16;
          Cf[base + col] = acc[m][n][r] + bias[col] + resid[base + col];
        }
      }
  } else {
    #pragma unroll
    for (int m = 0; m < 4; ++m)
      #pragma unroll
      for (int r = 0; r < 4; ++r){
        size_t base = (size_t)(orow0 + m*16 + r) * N;
        #pragma unroll
        for (int n = 0; n < 4; ++n)
          Cb[base + ocol0 + n*16] = f2b(acc[m][n][r]);
      }
  }
}

// ---------- k softmax stats, pass 1 ----------
__global__ __launch_bounds__(256) void k_kstats1(const u16* __restrict__ qkv,
    float* __restrict__ pm, float* __restrict__ ps){
  const int s = blockIdx.x, frel = blockIdx.y, c = threadIdx.x;
  const u16* base = qkv + (size_t)frel*9216*768 + (size_t)s*128*768 + 256 + c;
  float m0 = -1e30f, s0 = 0.f, m1 = -1e30f, s1 = 0.f;
  #pragma unroll 4
  for (int n = 0; n < 64; ++n){
    float v0 = b2f(base[(size_t)n*768]);
    float v1 = b2f(base[(size_t)(n+64)*768]);
    float nm0 = fmaxf(m0, v0); s0 = s0*__expf(m0-nm0) + __expf(v0-nm0); m0 = nm0;
    float nm1 = fmaxf(m1, v1); s1 = s1*__expf(m1-nm1) + __expf(v1-nm1); m1 = nm1;
  }
  float m = fmaxf(m0, m1);
  float sum = s0*__expf(m0-m) + s1*__expf(m1-m);
  size_t idx = ((size_t)frel*72 + s)*256 + c;
  pm[idx] = m; ps[idx] = sum;
}

// ---------- k softmax stats, pass 2 ----------
__global__ __launch_bounds__(256) void k_kstats2(const float* __restrict__ pm, const float* __restrict__ ps,
    float* __restrict__ kmax, float* __restrict__ kiz){
  int frel = blockIdx.x, c = threadIdx.x;
  size_t b = (size_t)frel*72*256 + c;
  float m = -1e30f;
  #pragma unroll 8
  for (int s = 0; s < 72; ++s) m = fmaxf(m, pm[b + s*256]);
  float sum = 0.f;
  #pragma unroll 8
  for (int s = 0; s < 72; ++s) sum += ps[b + s*256] * __expf(pm[b + s*256] - m);
  kmax[frel*256 + c] = m;
  kiz [frel*256 + c] = 1.0f/sum;
}

// ---------- ctx partials: ctx[dd,e] += softmax_k[dd,n] * v[e,n] ----------
__global__ __launch_bounds__(256) void k_ctx(const u16* __restrict__ qkv,
    const float* __restrict__ kmax, const float* __restrict__ kiz, float* __restrict__ ctxp){
  const int h = blockIdx.x, frel = blockIdx.y, s = blockIdx.z;
  const int t = threadIdx.x;
  const int lc = t & 31, lrow = t >> 5;
  const int e4 = (t & 7) * 4, dd = t >> 3;
  __shared__ float Ks[64][32];
  __shared__ float Vs[64][32];
  const u16* kb = qkv + (size_t)frel * 9216 * 768 + 256 + h * 32;
  const u16* vb = kb + 256;
  const float mx = kmax[frel*256 + h*32 + lc];
  const float iz = kiz [frel*256 + h*32 + lc];
  float acc0=0.f, acc1=0.f, acc2=0.f, acc3=0.f;
  const int nend = (s + 1) * 576;
  for (int n0 = s * 576; n0 < nend; n0 += 64){
    __syncthreads();
    #pragma unroll
    for (int ii = 0; ii < 8; ++ii){
      int nl = lrow + 8*ii;
      size_t off = (size_t)(n0 + nl) * 768;
      Ks[nl][lc] = __expf(b2f(kb[off + lc]) - mx) * iz;
      Vs[nl][lc] = b2f(vb[off + lc]);
    }
    __syncthreads();
    #pragma unroll
    for (int nn = 0; nn < 64; ++nn){
      float p = Ks[nn][dd];
      float4 v = *(const float4*)&Vs[nn][e4];
      acc0 += p*v.x; acc1 += p*v.y; acc2 += p*v.z; acc3 += p*v.w;
    }
  }
  float* cb = ctxp + (((size_t)frel*16 + s)*8 + h)*1024 + dd*32 + e4;
  cb[0]=acc0; cb[1]=acc1; cb[2]=acc2; cb[3]=acc3;
}

__global__ void k_ctxred(const float* __restrict__ ctxp, float* __restrict__ ctx){
  int frel = blockIdx.x, t = threadIdx.x;
  for (int i = t; i < 8192; i += 256){
    float s = 0.f;
    #pragma unroll
    for (int q = 0; q < 16; ++q) s += ctxp[((size_t)frel*16 + q)*8192 + i];
    ctx[(size_t)frel*8192 + i] = s;
  }
}

// ---------- per-(token,head) q channel-softmax * scale -> bf16 ----------
__global__ __launch_bounds__(256) void k_qsm(const u16* __restrict__ qkv, u16* __restrict__ qs, int ntok){
  int g = blockIdx.x * 256 + threadIdx.x;
  int tok = g >> 3, h = g & 7;
  if (tok >= ntok) return;
  const u16* src = qkv + (size_t)tok*768 + h*32;
  short8 v[4];
  #pragma unroll
  for (int i = 0; i < 4; ++i) v[i] = *(const short8*)(src + i*8);
  float f[32];
  #pragma unroll
  for (int i = 0; i < 4; ++i)
    #pragma unroll
    for (int j = 0; j < 8; ++j) f[i*8+j] = b2f((u16)v[i][j]);
  float m = f[0];
  #pragma unroll
  for (int i = 1; i < 32; ++i) m = fmaxf(m, f[i]);
  float s = 0.f;
  #pragma unroll
  for (int i = 0; i < 32; ++i){ float p = __expf(f[i] - m); f[i] = p; s += p; }
  float r = 0.17677669529663689f / s;
  u16* dst = qs + (size_t)tok*256 + h*32;
  #pragma unroll
  for (int i = 0; i < 4; ++i){
    short8 o;
    #pragma unroll
    for (int j = 0; j < 8; ++j) o[j] = (short)f2b(f[i*8+j] * r);
    *(short8*)(dst + i*8) = o;
  }
}

// ---------- Weff_f[l, h*32+dd] = sum_e ctx_f[h][dd,e] * Wcomb[l, h*32+e] ----------
__global__ __launch_bounds__(256) void k_weff(const float* __restrict__ ctx, const float* __restrict__ wcf,
    u16* __restrict__ weff){
  int l = blockIdx.x, frel = blockIdx.y, t = threadIdx.x;
  int h = t >> 5, dd = t & 31;
  const float* cr = ctx + (size_t)frel*8192 + h*1024 + dd*32;
  const float* wr = wcf + (size_t)l*256 + h*32;
  float s = 0.f;
  #pragma unroll
  for (int e = 0; e < 32; ++e) s += cr[e] * wr[e];
  weff[((size_t)frel*256 + l)*256 + t] = f2b(s);
}

extern "C" void kernel_launch(void* const* d_in, const int* in_sizes, int n_in,
                              void* d_out, int out_size, void* d_ws, size_t ws_size,
                              hipStream_t stream){
  const float* x     = (const float*)d_in[0];
  const float* w_qkv = (const float*)d_in[1];
  const float* w_out = (const float*)d_in[2];
  const float* b_out = (const float*)d_in[3];
  const float* w_lin = (const float*)d_in[4];
  const float* b_lin = (const float*)d_in[5];
  float* out = (float*)d_out;

  char* p = (char*)d_ws;
  u16*   wqb   = (u16*)p;   p += (size_t)768*256*2;
  float* wcf   = (float*)p; p += (size_t)256*256*4;
  float* bc    = (float*)p; p += 256*4;
  float* kmaxb = (float*)p; p += 8*256*4;
  float* kizb  = (float*)p; p += 8*256*4;
  float* pmb   = (float*)p; p += (size_t)8*72*256*4;
  float* psb   = (float*)p; p += (size_t)8*72*256*4;
  float* ctxpb = (float*)p; p += (size_t)8*16*8192*4;
  float* ctxb  = (float*)p; p += (size_t)8*8192*4;
  u16*   weffb = (u16*)p;   p += (size_t)8*256*256*2;
  size_t fixed = (size_t)(p - (char*)d_ws);
  size_t per_frame = (size_t)9216*256*2 + (size_t)9216*768*2 + (size_t)9216*256*2;
  int chunk = (ws_size >= fixed + 8*per_frame) ? 8 : 1;
  u16* xb   = (u16*)p;
  u16* qkvb = xb   + (size_t)chunk*9216*256;
  u16* qsmb = qkvb + (size_t)chunk*9216*768;

  // weight prep (once)
  hipLaunchKernelGGL(k_cvt, dim3(192), dim3(256), 0, stream, (const float4*)w_qkv, (ushort4*)wqb, 49152);
  hipLaunchKernelGGL(k_prepw, dim3(256), dim3(256), 0, stream, w_lin, w_out, b_out, b_lin, wcf, bc);

  for (int f0 = 0; f0 < 8; f0 += chunk){
    const float* xc = x  + (size_t)f0*9216*256;
    float*       oc = out + (size_t)f0*9216*256;
    const int M = chunk * 9216;
    const int n4 = M * 256 / 4;
    hipLaunchKernelGGL(k_cvt, dim3((n4 + 255)/256), dim3(256), 0, stream, (const float4*)xc, (ushort4*)xb, n4);
    hipLaunchKernelGGL((k_gemm_mfma<256>), dim3(M/128, 6), dim3(256), 0, stream,
                       xb, wqb, qkvb, (float*)nullptr, (const float*)nullptr, (const float*)nullptr,
                       M, 768, 0);
    hipLaunchKernelGGL(k_kstats1, dim3(72, chunk), dim3(256), 0, stream, qkvb, pmb, psb);
    hipLaunchKernelGGL(k_kstats2, dim3(chunk), dim3(256), 0, stream, pmb, psb, kmaxb, kizb);
    hipLaunchKernelGGL(k_ctx, dim3(8, chunk, 16), dim3(256), 0, stream, qkvb, kmaxb, kizb, ctxpb);
    hipLaunchKernelGGL(k_ctxred, dim3(chunk), dim3(256), 0, stream, ctxpb, ctxb);
    hipLaunchKernelGGL(k_qsm, dim3(M*8/256, 1), dim3(256), 0, stream, qkvb, qsmb, M);
    hipLaunchKernelGGL(k_weff, dim3(256, chunk), dim3(256), 0, stream,
                       ctxb, wcf, weffb + (size_t)f0*256*256);
    hipLaunchKernelGGL((k_gemm_mfma<256>), dim3(M/128, 2), dim3(256), 0, stream,
                       qsmb, weffb + (size_t)f0*256*256, (u16*)nullptr, oc, bc, xc,
                       M, 256, (chunk == 8) ? 9216 : 0);
  }
}

// Round 6
// 237.387 us; speedup vs baseline: 5.0835x; 1.0842x over previous
//
#include <hip/hip_runtime.h>

using u16 = unsigned short;
typedef __attribute__((ext_vector_type(8))) short short8;
typedef __attribute__((ext_vector_type(4))) float f32x4;

__device__ __forceinline__ float b2f(u16 u){ union{unsigned u; float f;} c; c.u = ((unsigned)u) << 16; return c.f; }
__device__ __forceinline__ u16 f2b(float f){
  union{float f; unsigned u;} c; c.f = f;
  unsigned r = 0x7fffu + ((c.u >> 16) & 1u);
  return (u16)((c.u + r) >> 16);
}

#define GLOAD_LDS16(g, l) __builtin_amdgcn_global_load_lds( \
  (const __attribute__((address_space(1))) unsigned int*)(g), \
  (__attribute__((address_space(3))) unsigned int*)(l), 16, 0, 0)

// ---------- f32 -> bf16 convert, 4/thread ----------
__global__ void k_cvt(const float4* __restrict__ in, ushort4* __restrict__ out, int n4){
  int i = blockIdx.x * 256 + threadIdx.x;
  if (i < n4){
    float4 v = in[i];
    ushort4 o; o.x = f2b(v.x); o.y = f2b(v.y); o.z = f2b(v.z); o.w = f2b(v.w);
    out[i] = o;
  }
}

// ---------- Wcomb = w_lin @ w_out (fp32), b_comb = w_lin@b_out + b_lin ----------
__global__ __launch_bounds__(256) void k_prepw(const float* __restrict__ w_lin, const float* __restrict__ w_out,
    const float* __restrict__ b_out, const float* __restrict__ b_lin,
    float* __restrict__ wcf, float* __restrict__ bc){
  int l = blockIdx.x, i = threadIdx.x;
  float s = 0.f;
  for (int j = 0; j < 256; ++j) s += w_lin[l*256 + j] * w_out[j*256 + i];
  wcf[l*256 + i] = s;
  __shared__ float red[256];
  red[i] = w_lin[l*256 + i] * b_out[i];
  __syncthreads();
  for (int off = 128; off > 0; off >>= 1){ if (i < off) red[i] += red[i + off]; __syncthreads(); }
  if (i == 0) bc[l] = red[0] + b_lin[l];
}

// ---------- MFMA bf16 GEMM: C[M,N] = A[M,K] @ B[N,K]^T ----------
// 128x128 tile, BK=32, 4 waves, 4x4 16x16x32 fragments.
// 3-deep LDS pipeline, 1 barrier/step, counted vmcnt(4).
// XCD swizzle: all NB n-blocks of an m-panel land consecutively on one XCD.
// Swizzle: phys chunk = logical ^ ((row>>1)&3), inverse pre-applied to global src.
template<int K>
__global__ __launch_bounds__(256, 3) void k_gemm_mfma(const u16* __restrict__ A, const u16* __restrict__ B,
    u16* __restrict__ Cb, float* __restrict__ Cf,
    const float* __restrict__ bias, const u16* __restrict__ residb,
    int M, int N, int NB, int frame_rows){
  __shared__ __align__(16) u16 As[3][128*32];
  __shared__ __align__(16) u16 Bs[3][128*32];
  const int t = threadIdx.x;
  const int wave = t >> 6, lane = t & 63;
  const int bi = blockIdx.x;
  const int xk = bi & 7, bj = bi >> 3;
  const int bm = (xk + 8*(bj/NB)) * 128, bn = (bj%NB) * 128;
  if (frame_rows > 0) B += (size_t)(bm / frame_rows) * N * K;
  const int srow = wave*32 + (lane>>2);
  const int skel = (((lane&3) ^ ((lane>>3)&3)) << 3);   // inverse-swizzled global k chunk
  const u16* ag = A + (size_t)(bm + srow)*K + skel;
  const u16* bg = B + (size_t)(bn + srow)*K + skel;
  const size_t rstep = (size_t)16*K;
  const int wr = (wave>>1)*64, wc4 = (wave&1)*64;
  const int fr = lane & 15;
  const int fkc = lane >> 4;
  const int koff = ((fkc ^ ((fr>>1)&3)) << 3);          // swizzled phys chunk on read
  constexpr int NT = K/32;
  f32x4 acc[4][4] = {};
  #pragma unroll
  for (int pre = 0; pre < 2; ++pre){
    u16* asl = As[pre] + wave*1024; u16* bsl = Bs[pre] + wave*1024;
    const int k0 = pre*32;
    GLOAD_LDS16(ag + k0,         asl);
    GLOAD_LDS16(ag + rstep + k0, asl + 512);
    GLOAD_LDS16(bg + k0,         bsl);
    GLOAD_LDS16(bg + rstep + k0, bsl + 512);
  }
  #pragma unroll
  for (int it = 0; it < NT; ++it){
    const int cur = it % 3;
    if (it == NT-1) { asm volatile("s_waitcnt vmcnt(0)" ::: "memory"); }
    else            { asm volatile("s_waitcnt vmcnt(4)" ::: "memory"); }
    __builtin_amdgcn_s_barrier();
    __builtin_amdgcn_sched_barrier(0);
    short8 av[4], bv[4];
    #pragma unroll
    for (int m = 0; m < 4; ++m)
      av[m] = *(const short8*)&As[cur][(wr + m*16 + fr)*32 + koff];
    #pragma unroll
    for (int n = 0; n < 4; ++n)
      bv[n] = *(const short8*)&Bs[cur][(wc4 + n*16 + fr)*32 + koff];
    if (it + 2 < NT){
      const int nb = (it+2) % 3;
      u16* asl = As[nb] + wave*1024; u16* bsl = Bs[nb] + wave*1024;
      const int k0 = (it+2)*32;
      GLOAD_LDS16(ag + k0,         asl);
      GLOAD_LDS16(ag + rstep + k0, asl + 512);
      GLOAD_LDS16(bg + k0,         bsl);
      GLOAD_LDS16(bg + rstep + k0, bsl + 512);
    }
    __builtin_amdgcn_s_setprio(1);
    #pragma unroll
    for (int m = 0; m < 4; ++m)
      #pragma unroll
      for (int n = 0; n < 4; ++n)
        acc[m][n] = __builtin_amdgcn_mfma_f32_16x16x32_bf16(av[m], bv[n], acc[m][n], 0, 0, 0);
    __builtin_amdgcn_s_setprio(0);
  }
  const int orow0 = bm + wr + (lane>>4)*4;
  const int ocol0 = bn + wc4 + fr;
  if (Cf){
    #pragma unroll
    for (int m = 0; m < 4; ++m)
      #pragma unroll
      for (int r = 0; r < 4; ++r){
        size_t base = (size_t)(orow0 + m*16 + r) * N;
        #pragma unroll
        for (int n = 0; n < 4; ++n){
          int col = ocol0 + n*16;
          Cf[base + col] = acc[m][n][r] + bias[col] + b2f(residb[base + col]);
        }
      }
  } else {
    #pragma unroll
    for (int m = 0; m < 4; ++m)
      #pragma unroll
      for (int r = 0; r < 4; ++r){
        size_t base = (size_t)(orow0 + m*16 + r) * N;
        #pragma unroll
        for (int n = 0; n < 4; ++n)
          Cb[base + ocol0 + n*16] = f2b(acc[m][n][r]);
      }
  }
}

// ---------- k softmax stats, pass 1 ----------
__global__ __launch_bounds__(256) void k_kstats1(const u16* __restrict__ qkv,
    float* __restrict__ pm, float* __restrict__ ps){
  const int s = blockIdx.x, frel = blockIdx.y, c = threadIdx.x;
  const u16* base = qkv + (size_t)frel*9216*768 + (size_t)s*128*768 + 256 + c;
  float m0 = -1e30f, s0 = 0.f, m1 = -1e30f, s1 = 0.f;
  #pragma unroll 4
  for (int n = 0; n < 64; ++n){
    float v0 = b2f(base[(size_t)n*768]);
    float v1 = b2f(base[(size_t)(n+64)*768]);
    float nm0 = fmaxf(m0, v0); s0 = s0*__expf(m0-nm0) + __expf(v0-nm0); m0 = nm0;
    float nm1 = fmaxf(m1, v1); s1 = s1*__expf(m1-nm1) + __expf(v1-nm1); m1 = nm1;
  }
  float m = fmaxf(m0, m1);
  float sum = s0*__expf(m0-m) + s1*__expf(m1-m);
  size_t idx = ((size_t)frel*72 + s)*256 + c;
  pm[idx] = m; ps[idx] = sum;
}

// ---------- k softmax stats, pass 2 ----------
__global__ __launch_bounds__(256) void k_kstats2(const float* __restrict__ pm, const float* __restrict__ ps,
    float* __restrict__ kmax, float* __restrict__ kiz){
  int frel = blockIdx.x, c = threadIdx.x;
  size_t b = (size_t)frel*72*256 + c;
  float m = -1e30f;
  #pragma unroll 8
  for (int s = 0; s < 72; ++s) m = fmaxf(m, pm[b + s*256]);
  float sum = 0.f;
  #pragma unroll 8
  for (int s = 0; s < 72; ++s) sum += ps[b + s*256] * __expf(pm[b + s*256] - m);
  kmax[frel*256 + c] = m;
  kiz [frel*256 + c] = 1.0f/sum;
}

// ---------- ctx partials: ctx[dd,e] += softmax_k[dd,n] * v[e,n] ----------
__global__ __launch_bounds__(256) void k_ctx(const u16* __restrict__ qkv,
    const float* __restrict__ kmax, const float* __restrict__ kiz, float* __restrict__ ctxp){
  const int h = blockIdx.x, frel = blockIdx.y, s = blockIdx.z;
  const int t = threadIdx.x;
  const int lc = t & 31, lrow = t >> 5;
  const int e4 = (t & 7) * 4, dd = t >> 3;
  __shared__ float Ks[64][32];
  __shared__ float Vs[64][32];
  const u16* kb = qkv + (size_t)frel * 9216 * 768 + 256 + h * 32;
  const u16* vb = kb + 256;
  const float mx = kmax[frel*256 + h*32 + lc];
  const float iz = kiz [frel*256 + h*32 + lc];
  float acc0=0.f, acc1=0.f, acc2=0.f, acc3=0.f;
  const int nend = (s + 1) * 576;
  for (int n0 = s * 576; n0 < nend; n0 += 64){
    __syncthreads();
    #pragma unroll
    for (int ii = 0; ii < 8; ++ii){
      int nl = lrow + 8*ii;
      size_t off = (size_t)(n0 + nl) * 768;
      Ks[nl][lc] = __expf(b2f(kb[off + lc]) - mx) * iz;
      Vs[nl][lc] = b2f(vb[off + lc]);
    }
    __syncthreads();
    #pragma unroll
    for (int nn = 0; nn < 64; ++nn){
      float p = Ks[nn][dd];
      float4 v = *(const float4*)&Vs[nn][e4];
      acc0 += p*v.x; acc1 += p*v.y; acc2 += p*v.z; acc3 += p*v.w;
    }
  }
  float* cb = ctxp + (((size_t)frel*16 + s)*8 + h)*1024 + dd*32 + e4;
  cb[0]=acc0; cb[1]=acc1; cb[2]=acc2; cb[3]=acc3;
}

__global__ void k_ctxred(const float* __restrict__ ctxp, float* __restrict__ ctx){
  int frel = blockIdx.x, t = threadIdx.x;
  for (int i = t; i < 8192; i += 256){
    float s = 0.f;
    #pragma unroll
    for (int q = 0; q < 16; ++q) s += ctxp[((size_t)frel*16 + q)*8192 + i];
    ctx[(size_t)frel*8192 + i] = s;
  }
}

// ---------- per-(token,head) q channel-softmax * scale -> bf16 ----------
__global__ __launch_bounds__(256) void k_qsm(const u16* __restrict__ qkv, u16* __restrict__ qs, int ntok){
  int g = blockIdx.x * 256 + threadIdx.x;
  int tok = g >> 3, h = g & 7;
  if (tok >= ntok) return;
  const u16* src = qkv + (size_t)tok*768 + h*32;
  short8 v[4];
  #pragma unroll
  for (int i = 0; i < 4; ++i) v[i] = *(const short8*)(src + i*8);
  float f[32];
  #pragma unroll
  for (int i = 0; i < 4; ++i)
    #pragma unroll
    for (int j = 0; j < 8; ++j) f[i*8+j] = b2f((u16)v[i][j]);
  float m = f[0];
  #pragma unroll
  for (int i = 1; i < 32; ++i) m = fmaxf(m, f[i]);
  float s = 0.f;
  #pragma unroll
  for (int i = 0; i < 32; ++i){ float p = __expf(f[i] - m); f[i] = p; s += p; }
  float r = 0.17677669529663689f / s;
  u16* dst = qs + (size_t)tok*256 + h*32;
  #pragma unroll
  for (int i = 0; i < 4; ++i){
    short8 o;
    #pragma unroll
    for (int j = 0; j < 8; ++j) o[j] = (short)f2b(f[i*8+j] * r);
    *(short8*)(dst + i*8) = o;
  }
}

// ---------- Weff_f[l, h*32+dd] = sum_e ctx_f[h][dd,e] * Wcomb[l, h*32+e] ----------
__global__ __launch_bounds__(256) void k_weff(const float* __restrict__ ctx, const float* __restrict__ wcf,
    u16* __restrict__ weff){
  int l = blockIdx.x, frel = blockIdx.y, t = threadIdx.x;
  int h = t >> 5, dd = t & 31;
  const float* cr = ctx + (size_t)frel*8192 + h*1024 + dd*32;
  const float* wr = wcf + (size_t)l*256 + h*32;
  float s = 0.f;
  #pragma unroll
  for (int e = 0; e < 32; ++e) s += cr[e] * wr[e];
  weff[((size_t)frel*256 + l)*256 + t] = f2b(s);
}

extern "C" void kernel_launch(void* const* d_in, const int* in_sizes, int n_in,
                              void* d_out, int out_size, void* d_ws, size_t ws_size,
                              hipStream_t stream){
  const float* x     = (const float*)d_in[0];
  const float* w_qkv = (const float*)d_in[1];
  const float* w_out = (const float*)d_in[2];
  const float* b_out = (const float*)d_in[3];
  const float* w_lin = (const float*)d_in[4];
  const float* b_lin = (const float*)d_in[5];
  float* out = (float*)d_out;

  char* p = (char*)d_ws;
  u16*   wqb   = (u16*)p;   p += (size_t)768*256*2;
  float* wcf   = (float*)p; p += (size_t)256*256*4;
  float* bc    = (float*)p; p += 256*4;
  float* kmaxb = (float*)p; p += 8*256*4;
  float* kizb  = (float*)p; p += 8*256*4;
  float* pmb   = (float*)p; p += (size_t)8*72*256*4;
  float* psb   = (float*)p; p += (size_t)8*72*256*4;
  float* ctxpb = (float*)p; p += (size_t)8*16*8192*4;
  float* ctxb  = (float*)p; p += (size_t)8*8192*4;
  u16*   weffb = (u16*)p;   p += (size_t)8*256*256*2;
  size_t fixed = (size_t)(p - (char*)d_ws);
  size_t per_frame = (size_t)9216*256*2 + (size_t)9216*768*2 + (size_t)9216*256*2;
  int chunk = (ws_size >= fixed + 8*per_frame) ? 8 : 1;
  u16* xb   = (u16*)p;
  u16* qkvb = xb   + (size_t)chunk*9216*256;
  u16* qsmb = qkvb + (size_t)chunk*9216*768;

  // weight prep (once)
  hipLaunchKernelGGL(k_cvt, dim3(192), dim3(256), 0, stream, (const float4*)w_qkv, (ushort4*)wqb, 49152);
  hipLaunchKernelGGL(k_prepw, dim3(256), dim3(256), 0, stream, w_lin, w_out, b_out, b_lin, wcf, bc);

  for (int f0 = 0; f0 < 8; f0 += chunk){
    const float* xc = x  + (size_t)f0*9216*256;
    float*       oc = out + (size_t)f0*9216*256;
    const int M = chunk * 9216;
    const int n4 = M * 256 / 4;
    hipLaunchKernelGGL(k_cvt, dim3((n4 + 255)/256), dim3(256), 0, stream, (const float4*)xc, (ushort4*)xb, n4);
    hipLaunchKernelGGL((k_gemm_mfma<256>), dim3((M/128)*6), dim3(256), 0, stream,
                       xb, wqb, qkvb, (float*)nullptr, (const float*)nullptr, (const u16*)nullptr,
                       M, 768, 6, 0);
    hipLaunchKernelGGL(k_kstats1, dim3(72, chunk), dim3(256), 0, stream, qkvb, pmb, psb);
    hipLaunchKernelGGL(k_kstats2, dim3(chunk), dim3(256), 0, stream, pmb, psb, kmaxb, kizb);
    hipLaunchKernelGGL(k_ctx, dim3(8, chunk, 16), dim3(256), 0, stream, qkvb, kmaxb, kizb, ctxpb);
    hipLaunchKernelGGL(k_ctxred, dim3(chunk), dim3(256), 0, stream, ctxpb, ctxb);
    hipLaunchKernelGGL(k_qsm, dim3(M*8/256, 1), dim3(256), 0, stream, qkvb, qsmb, M);
    hipLaunchKernelGGL(k_weff, dim3(256, chunk), dim3(256), 0, stream,
                       ctxb, wcf, weffb + (size_t)f0*256*256);
    hipLaunchKernelGGL((k_gemm_mfma<256>), dim3((M/128)*2), dim3(256), 0, stream,
                       qsmb, weffb + (size_t)f0*256*256, (u16*)nullptr, oc, bc, xb,
                       M, 256, 2, (chunk == 8) ? 9216 : 0);
  }
}

// Round 8
// 204.618 us; speedup vs baseline: 5.8976x; 1.1601x over previous
//
#include <hip/hip_runtime.h>

using u16 = unsigned short;
typedef __attribute__((ext_vector_type(8))) short short8;
typedef __attribute__((ext_vector_type(4))) float f32x4;

__device__ __forceinline__ float b2f(u16 u){ union{unsigned u; float f;} c; c.u = ((unsigned)u) << 16; return c.f; }
__device__ __forceinline__ u16 f2b(float f){
  union{float f; unsigned u;} c; c.f = f;
  unsigned r = 0x7fffu + ((c.u >> 16) & 1u);
  return (u16)((c.u + r) >> 16);
}
__device__ __forceinline__ float rb(float f){ return b2f(f2b(f)); }

#define GLOAD_LDS16(g, l) __builtin_amdgcn_global_load_lds( \
  (const __attribute__((address_space(1))) unsigned int*)(g), \
  (__attribute__((address_space(3))) unsigned int*)(l), 16, 0, 0)

// ---------- f32 -> bf16 convert, 4/thread ----------
__global__ void k_cvt(const float4* __restrict__ in, ushort4* __restrict__ out, int n4){
  int i = blockIdx.x * 256 + threadIdx.x;
  if (i < n4){
    float4 v = in[i];
    ushort4 o; o.x = f2b(v.x); o.y = f2b(v.y); o.z = f2b(v.z); o.w = f2b(v.w);
    out[i] = o;
  }
}

// ---------- Wcomb = w_lin @ w_out (fp32), b_comb = w_lin@b_out + b_lin ----------
__global__ __launch_bounds__(256) void k_prepw(const float* __restrict__ w_lin, const float* __restrict__ w_out,
    const float* __restrict__ b_out, const float* __restrict__ b_lin,
    float* __restrict__ wcf, float* __restrict__ bc){
  int l = blockIdx.x, i = threadIdx.x;
  float s = 0.f;
  for (int j = 0; j < 256; ++j) s += w_lin[l*256 + j] * w_out[j*256 + i];
  wcf[l*256 + i] = s;
  __shared__ float red[256];
  red[i] = w_lin[l*256 + i] * b_out[i];
  __syncthreads();
  for (int off = 128; off > 0; off >>= 1){ if (i < off) red[i] += red[i + off]; __syncthreads(); }
  if (i == 0) bc[l] = red[0] + b_lin[l];
}

// ---------- fused QKV GEMM: qkv = X @ Wqkv^T, with q-softmax + k-stats epilogues ----------
// 128x128 tile, BK=32, 4 waves, 4x4 16x16x32 frags, 3-deep pipeline, 1 barrier/step.
// bn 0,1: q -> per-(row,head) softmax*scale -> qs (q NOT written to qkv)
// bn 2,3: k -> qkv + per-column (max,sumexp) partials over 128 rows -> pm/ps
// bn 4,5: v -> qkv
__global__ __launch_bounds__(256, 3) void k_gemm_qkv(const u16* __restrict__ A, const u16* __restrict__ B,
    u16* __restrict__ qkv, u16* __restrict__ qs,
    float* __restrict__ pm, float* __restrict__ ps, int M){
  constexpr int K = 256, NT = 8;
  __shared__ __align__(16) u16 As[3][128*32];
  __shared__ __align__(16) u16 Bs[3][128*32];
  __shared__ float redm[2][2][64], reds[2][2][64];
  const int t = threadIdx.x;
  const int wave = t >> 6, lane = t & 63;
  const int bi = blockIdx.x;
  const int xk = bi & 7, bj = bi >> 3;
  const int bm = (xk + 8*(bj/6)) * 128;
  const int bn = bj % 6;
  const int srow = wave*32 + (lane>>2);
  const int skel = (((lane&3) ^ ((lane>>3)&3)) << 3);
  const u16* ag = A + (size_t)(bm + srow)*K + skel;
  const u16* bg = B + (size_t)(bn*128 + srow)*K + skel;
  const size_t rstep = (size_t)16*K;
  const int wr = (wave>>1)*64, wc4 = (wave&1)*64;
  const int fr = lane & 15;
  const int fkc = lane >> 4;
  const int koff = ((fkc ^ ((fr>>1)&3)) << 3);
  f32x4 acc[4][4] = {};
  #pragma unroll
  for (int pre = 0; pre < 2; ++pre){
    u16* asl = As[pre] + wave*1024; u16* bsl = Bs[pre] + wave*1024;
    const int k0 = pre*32;
    GLOAD_LDS16(ag + k0,         asl);
    GLOAD_LDS16(ag + rstep + k0, asl + 512);
    GLOAD_LDS16(bg + k0,         bsl);
    GLOAD_LDS16(bg + rstep + k0, bsl + 512);
  }
  #pragma unroll
  for (int it = 0; it < NT; ++it){
    const int cur = it % 3;
    if (it == NT-1) { asm volatile("s_waitcnt vmcnt(0)" ::: "memory"); }
    else            { asm volatile("s_waitcnt vmcnt(4)" ::: "memory"); }
    __builtin_amdgcn_s_barrier();
    __builtin_amdgcn_sched_barrier(0);
    short8 av[4], bv[4];
    #pragma unroll
    for (int m = 0; m < 4; ++m)
      av[m] = *(const short8*)&As[cur][(wr + m*16 + fr)*32 + koff];
    #pragma unroll
    for (int n = 0; n < 4; ++n)
      bv[n] = *(const short8*)&Bs[cur][(wc4 + n*16 + fr)*32 + koff];
    if (it + 2 < NT){
      const int nb = (it+2) % 3;
      u16* asl = As[nb] + wave*1024; u16* bsl = Bs[nb] + wave*1024;
      const int k0 = (it+2)*32;
      GLOAD_LDS16(ag + k0,         asl);
      GLOAD_LDS16(ag + rstep + k0, asl + 512);
      GLOAD_LDS16(bg + k0,         bsl);
      GLOAD_LDS16(bg + rstep + k0, bsl + 512);
    }
    __builtin_amdgcn_s_setprio(1);
    #pragma unroll
    for (int m = 0; m < 4; ++m)
      #pragma unroll
      for (int n = 0; n < 4; ++n)
        acc[m][n] = __builtin_amdgcn_mfma_f32_16x16x32_bf16(av[m], bv[n], acc[m][n], 0, 0, 0);
    __builtin_amdgcn_s_setprio(0);
  }
  const int orow0 = bm + wr + (lane>>4)*4;
  if (bn < 2){
    // q-softmax over 32 channels/head: 2 frags x 16 lanes of this lane-group
    #pragma unroll
    for (int j = 0; j < 2; ++j){
      #pragma unroll
      for (int m = 0; m < 4; ++m)
        #pragma unroll
        for (int r = 0; r < 4; ++r){
          float a0 = acc[m][2*j][r], a1 = acc[m][2*j+1][r];
          float mx = fmaxf(a0, a1);
          mx = fmaxf(mx, __shfl_xor(mx, 1, 64));
          mx = fmaxf(mx, __shfl_xor(mx, 2, 64));
          mx = fmaxf(mx, __shfl_xor(mx, 4, 64));
          mx = fmaxf(mx, __shfl_xor(mx, 8, 64));
          float e0 = __expf(a0 - mx), e1 = __expf(a1 - mx);
          float sum = e0 + e1;
          sum += __shfl_xor(sum, 1, 64);
          sum += __shfl_xor(sum, 2, 64);
          sum += __shfl_xor(sum, 4, 64);
          sum += __shfl_xor(sum, 8, 64);
          float sc = 0.17677669529663689f / sum;
          size_t base = (size_t)(orow0 + m*16 + r) * 256 + bn*128 + wc4 + j*32 + fr;
          qs[base]      = f2b(e0 * sc);
          qs[base + 16] = f2b(e1 * sc);
        }
    }
  } else {
    const int ocol0 = bn*128 + wc4 + fr;
    #pragma unroll
    for (int m = 0; m < 4; ++m)
      #pragma unroll
      for (int r = 0; r < 4; ++r){
        size_t base = (size_t)(orow0 + m*16 + r) * 768;
        #pragma unroll
        for (int n = 0; n < 4; ++n)
          qkv[base + ocol0 + n*16] = f2b(acc[m][n][r]);
      }
    if (bn < 4){
      // per-column stats over this block's 128 rows (on rounded values)
      #pragma unroll
      for (int n = 0; n < 4; ++n){
        float mx = -1e30f;
        #pragma unroll
        for (int m = 0; m < 4; ++m)
          #pragma unroll
          for (int r = 0; r < 4; ++r)
            mx = fmaxf(mx, rb(acc[m][n][r]));
        mx = fmaxf(mx, __shfl_xor(mx, 16, 64));
        mx = fmaxf(mx, __shfl_xor(mx, 32, 64));
        float sum = 0.f;
        #pragma unroll
        for (int m = 0; m < 4; ++m)
          #pragma unroll
          for (int r = 0; r < 4; ++r)
            sum += __expf(rb(acc[m][n][r]) - mx);
        sum += __shfl_xor(sum, 16, 64);
        sum += __shfl_xor(sum, 32, 64);
        if (lane < 16){
          redm[wave>>1][wave&1][n*16 + lane] = mx;
          reds[wave>>1][wave&1][n*16 + lane] = sum;
        }
      }
      __syncthreads();
      if (t < 128){
        int half = t >> 6, cc = t & 63;
        float ma = redm[0][half][cc], mb2 = redm[1][half][cc];
        float m2 = fmaxf(ma, mb2);
        float s2 = reds[0][half][cc]*__expf(ma - m2) + reds[1][half][cc]*__expf(mb2 - m2);
        int frame = bm / 9216, mrel = (bm % 9216) >> 7;
        size_t idx = ((size_t)frame*72 + mrel)*256 + (size_t)(bn-2)*128 + t;
        pm[idx] = m2; ps[idx] = s2;
      }
    }
  }
}

// ---------- generic MFMA GEMM (used for the output GEMM) ----------
template<int K>
__global__ __launch_bounds__(256, 3) void k_gemm_mfma(const u16* __restrict__ A, const u16* __restrict__ B,
    u16* __restrict__ Cb, float* __restrict__ Cf,
    const float* __restrict__ bias, const u16* __restrict__ residb,
    int M, int N, int NB, int frame_rows){
  __shared__ __align__(16) u16 As[3][128*32];
  __shared__ __align__(16) u16 Bs[3][128*32];
  const int t = threadIdx.x;
  const int wave = t >> 6, lane = t & 63;
  const int bi = blockIdx.x;
  const int xk = bi & 7, bj = bi >> 3;
  const int bm = (xk + 8*(bj/NB)) * 128, bn = (bj%NB) * 128;
  if (frame_rows > 0) B += (size_t)(bm / frame_rows) * N * K;
  const int srow = wave*32 + (lane>>2);
  const int skel = (((lane&3) ^ ((lane>>3)&3)) << 3);
  const u16* ag = A + (size_t)(bm + srow)*K + skel;
  const u16* bg = B + (size_t)(bn + srow)*K + skel;
  const size_t rstep = (size_t)16*K;
  const int wr = (wave>>1)*64, wc4 = (wave&1)*64;
  const int fr = lane & 15;
  const int fkc = lane >> 4;
  const int koff = ((fkc ^ ((fr>>1)&3)) << 3);
  constexpr int NT = K/32;
  f32x4 acc[4][4] = {};
  #pragma unroll
  for (int pre = 0; pre < 2; ++pre){
    u16* asl = As[pre] + wave*1024; u16* bsl = Bs[pre] + wave*1024;
    const int k0 = pre*32;
    GLOAD_LDS16(ag + k0,         asl);
    GLOAD_LDS16(ag + rstep + k0, asl + 512);
    GLOAD_LDS16(bg + k0,         bsl);
    GLOAD_LDS16(bg + rstep + k0, bsl + 512);
  }
  #pragma unroll
  for (int it = 0; it < NT; ++it){
    const int cur = it % 3;
    if (it == NT-1) { asm volatile("s_waitcnt vmcnt(0)" ::: "memory"); }
    else            { asm volatile("s_waitcnt vmcnt(4)" ::: "memory"); }
    __builtin_amdgcn_s_barrier();
    __builtin_amdgcn_sched_barrier(0);
    short8 av[4], bv[4];
    #pragma unroll
    for (int m = 0; m < 4; ++m)
      av[m] = *(const short8*)&As[cur][(wr + m*16 + fr)*32 + koff];
    #pragma unroll
    for (int n = 0; n < 4; ++n)
      bv[n] = *(const short8*)&Bs[cur][(wc4 + n*16 + fr)*32 + koff];
    if (it + 2 < NT){
      const int nb = (it+2) % 3;
      u16* asl = As[nb] + wave*1024; u16* bsl = Bs[nb] + wave*1024;
      const int k0 = (it+2)*32;
      GLOAD_LDS16(ag + k0,         asl);
      GLOAD_LDS16(ag + rstep + k0, asl + 512);
      GLOAD_LDS16(bg + k0,         bsl);
      GLOAD_LDS16(bg + rstep + k0, bsl + 512);
    }
    __builtin_amdgcn_s_setprio(1);
    #pragma unroll
    for (int m = 0; m < 4; ++m)
      #pragma unroll
      for (int n = 0; n < 4; ++n)
        acc[m][n] = __builtin_amdgcn_mfma_f32_16x16x32_bf16(av[m], bv[n], acc[m][n], 0, 0, 0);
    __builtin_amdgcn_s_setprio(0);
  }
  const int orow0 = bm + wr + (lane>>4)*4;
  const int ocol0 = bn + wc4 + fr;
  if (Cf){
    #pragma unroll
    for (int m = 0; m < 4; ++m)
      #pragma unroll
      for (int r = 0; r < 4; ++r){
        size_t base = (size_t)(orow0 + m*16 + r) * N;
        #pragma unroll
        for (int n = 0; n < 4; ++n){
          int col = ocol0 + n*16;
          Cf[base + col] = acc[m][n][r] + bias[col] + b2f(residb[base + col]);
        }
      }
  } else {
    #pragma unroll
    for (int m = 0; m < 4; ++m)
      #pragma unroll
      for (int r = 0; r < 4; ++r){
        size_t base = (size_t)(orow0 + m*16 + r) * N;
        #pragma unroll
        for (int n = 0; n < 4; ++n)
          Cb[base + ocol0 + n*16] = f2b(acc[m][n][r]);
      }
  }
}

// ---------- k softmax stats, pass 2: reduce 72 per-block partials ----------
__global__ __launch_bounds__(256) void k_kstats2(const float* __restrict__ pm, const float* __restrict__ ps,
    float* __restrict__ kmax, float* __restrict__ kiz){
  int frel = blockIdx.x, c = threadIdx.x;
  size_t b = (size_t)frel*72*256 + c;
  float m = -1e30f;
  #pragma unroll 8
  for (int s = 0; s < 72; ++s) m = fmaxf(m, pm[b + s*256]);
  float sum = 0.f;
  #pragma unroll 8
  for (int s = 0; s < 72; ++s) sum += ps[b + s*256] * __expf(pm[b + s*256] - m);
  kmax[frel*256 + c] = m;
  kiz [frel*256 + c] = 1.0f/sum;
}

// ---------- ctx partials: ctx[dd,e] += softmax_k[dd,n] * v[e,n] ----------
// register-blocked 4x4 per thread; tq splits the 64-token tile 16 each.
__global__ __launch_bounds__(256) void k_ctx(const u16* __restrict__ qkv,
    const float* __restrict__ kmax, const float* __restrict__ kiz, float* __restrict__ ctxp){
  const int h = blockIdx.x, frel = blockIdx.y, s = blockIdx.z;
  const int t = threadIdx.x;
  const int lc = t & 31, lrow = t >> 5;
  const int tq = t >> 6;
  const int d0 = ((t >> 3) & 7) * 4;
  const int e0 = (t & 7) * 4;
  __shared__ float Ks[64][32];
  __shared__ float Vs[64][32];
  __shared__ float red[4][1024];
  const u16* kb = qkv + (size_t)frel * 9216 * 768 + 256 + h * 32;
  const u16* vb = kb + 256;
  const float mx = kmax[frel*256 + h*32 + lc];
  const float iz = kiz [frel*256 + h*32 + lc];
  float acc[4][4] = {};
  const int nend = (s + 1) * 576;
  for (int n0 = s * 576; n0 < nend; n0 += 64){
    __syncthreads();
    #pragma unroll
    for (int ii = 0; ii < 8; ++ii){
      int nl = lrow + 8*ii;
      size_t off = (size_t)(n0 + nl) * 768;
      Ks[nl][lc] = __expf(b2f(kb[off + lc]) - mx) * iz;
      Vs[nl][lc] = b2f(vb[off + lc]);
    }
    __syncthreads();
    #pragma unroll
    for (int q2 = 0; q2 < 16; ++q2){
      int nn = tq*16 + q2;
      float4 kk = *(const float4*)&Ks[nn][d0];
      float4 vv = *(const float4*)&Vs[nn][e0];
      acc[0][0] += kk.x*vv.x; acc[0][1] += kk.x*vv.y; acc[0][2] += kk.x*vv.z; acc[0][3] += kk.x*vv.w;
      acc[1][0] += kk.y*vv.x; acc[1][1] += kk.y*vv.y; acc[1][2] += kk.y*vv.z; acc[1][3] += kk.y*vv.w;
      acc[2][0] += kk.z*vv.x; acc[2][1] += kk.z*vv.y; acc[2][2] += kk.z*vv.z; acc[2][3] += kk.z*vv.w;
      acc[3][0] += kk.w*vv.x; acc[3][1] += kk.w*vv.y; acc[3][2] += kk.w*vv.z; acc[3][3] += kk.w*vv.w;
    }
  }
  __syncthreads();
  #pragma unroll
  for (int i = 0; i < 4; ++i)
    #pragma unroll
    for (int j = 0; j < 4; ++j)
      red[tq][(d0+i)*32 + e0 + j] = acc[i][j];
  __syncthreads();
  float* cb = ctxp + (((size_t)frel*16 + s)*8 + h)*1024;
  for (int idx = t; idx < 1024; idx += 256)
    cb[idx] = red[0][idx] + red[1][idx] + red[2][idx] + red[3][idx];
}

__global__ void k_ctxred(const float* __restrict__ ctxp, float* __restrict__ ctx){
  int frel = blockIdx.x, t = threadIdx.x;
  for (int i = t; i < 8192; i += 256){
    float s = 0.f;
    #pragma unroll
    for (int q = 0; q < 16; ++q) s += ctxp[((size_t)frel*16 + q)*8192 + i];
    ctx[(size_t)frel*8192 + i] = s;
  }
}

// ---------- Weff_f[l, h*32+dd] = sum_e ctx_f[h][dd,e] * Wcomb[l, h*32+e] ----------
__global__ __launch_bounds__(256) void k_weff(const float* __restrict__ ctx, const float* __restrict__ wcf,
    u16* __restrict__ weff){
  int l = blockIdx.x, frel = blockIdx.y, t = threadIdx.x;
  int h = t >> 5, dd = t & 31;
  const float* cr = ctx + (size_t)frel*8192 + h*1024 + dd*32;
  const float* wr = wcf + (size_t)l*256 + h*32;
  float s = 0.f;
  #pragma unroll
  for (int e = 0; e < 32; ++e) s += cr[e] * wr[e];
  weff[((size_t)frel*256 + l)*256 + t] = f2b(s);
}

extern "C" void kernel_launch(void* const* d_in, const int* in_sizes, int n_in,
                              void* d_out, int out_size, void* d_ws, size_t ws_size,
                              hipStream_t stream){
  const float* x     = (const float*)d_in[0];
  const float* w_qkv = (const float*)d_in[1];
  const float* w_out = (const float*)d_in[2];
  const float* b_out = (const float*)d_in[3];
  const float* w_lin = (const float*)d_in[4];
  const float* b_lin = (const float*)d_in[5];
  float* out = (float*)d_out;

  char* p = (char*)d_ws;
  u16*   wqb   = (u16*)p;   p += (size_t)768*256*2;
  float* wcf   = (float*)p; p += (size_t)256*256*4;
  float* bc    = (float*)p; p += 256*4;
  float* kmaxb = (float*)p; p += 8*256*4;
  float* kizb  = (float*)p; p += 8*256*4;
  float* pmb   = (float*)p; p += (size_t)8*72*256*4;
  float* psb   = (float*)p; p += (size_t)8*72*256*4;
  float* ctxpb = (float*)p; p += (size_t)8*16*8192*4;
  float* ctxb  = (float*)p; p += (size_t)8*8192*4;
  u16*   weffb = (u16*)p;   p += (size_t)8*256*256*2;
  size_t fixed = (size_t)(p - (char*)d_ws);
  size_t per_frame = (size_t)9216*256*2 + (size_t)9216*768*2 + (size_t)9216*256*2;
  int chunk = (ws_size >= fixed + 8*per_frame) ? 8 : 1;
  u16* xb   = (u16*)p;
  u16* qkvb = xb   + (size_t)chunk*9216*256;
  u16* qsmb = qkvb + (size_t)chunk*9216*768;

  // weight prep (once)
  hipLaunchKernelGGL(k_cvt, dim3(192), dim3(256), 0, stream, (const float4*)w_qkv, (ushort4*)wqb, 49152);
  hipLaunchKernelGGL(k_prepw, dim3(256), dim3(256), 0, stream, w_lin, w_out, b_out, b_lin, wcf, bc);

  for (int f0 = 0; f0 < 8; f0 += chunk){
    const float* xc = x  + (size_t)f0*9216*256;
    float*       oc = out + (size_t)f0*9216*256;
    const int M = chunk * 9216;
    const int n4 = M * 256 / 4;
    hipLaunchKernelGGL(k_cvt, dim3((n4 + 255)/256), dim3(256), 0, stream, (const float4*)xc, (ushort4*)xb, n4);
    hipLaunchKernelGGL(k_gemm_qkv, dim3((M/128)*6), dim3(256), 0, stream,
                       xb, wqb, qkvb, qsmb, pmb, psb, M);
    hipLaunchKernelGGL(k_kstats2, dim3(chunk), dim3(256), 0, stream, pmb, psb, kmaxb, kizb);
    hipLaunchKernelGGL(k_ctx, dim3(8, chunk, 16), dim3(256), 0, stream, qkvb, kmaxb, kizb, ctxpb);
    hipLaunchKernelGGL(k_ctxred, dim3(chunk), dim3(256), 0, stream, ctxpb, ctxb);
    hipLaunchKernelGGL(k_weff, dim3(256, chunk), dim3(256), 0, stream,
                       ctxb, wcf, weffb + (size_t)f0*256*256);
    hipLaunchKernelGGL((k_gemm_mfma<256>), dim3((M/128)*2), dim3(256), 0, stream,
                       qsmb, weffb + (size_t)f0*256*256, (u16*)nullptr, oc, bc, xb,
                       M, 256, 2, (chunk == 8) ? 9216 : 0);
  }
}

// Round 9
// 197.386 us; speedup vs baseline: 6.1136x; 1.0366x over previous
//
#include <hip/hip_runtime.h>

using u16 = unsigned short;
typedef __attribute__((ext_vector_type(8))) short short8;
typedef __attribute__((ext_vector_type(4))) float f32x4;

__device__ __forceinline__ float b2f(u16 u){ union{unsigned u; float f;} c; c.u = ((unsigned)u) << 16; return c.f; }
__device__ __forceinline__ u16 f2b(float f){
  union{float f; unsigned u;} c; c.f = f;
  unsigned r = 0x7fffu + ((c.u >> 16) & 1u);
  return (u16)((c.u + r) >> 16);
}
__device__ __forceinline__ float rb(float f){ return b2f(f2b(f)); }

#define GLOAD_LDS16(g, l) __builtin_amdgcn_global_load_lds( \
  (const __attribute__((address_space(1))) unsigned int*)(g), \
  (__attribute__((address_space(3))) unsigned int*)(l), 16, 0, 0)

// ---------- f32 -> bf16 convert, 4/thread ----------
__global__ void k_cvt(const float4* __restrict__ in, ushort4* __restrict__ out, int n4){
  int i = blockIdx.x * 256 + threadIdx.x;
  if (i < n4){
    float4 v = in[i];
    ushort4 o; o.x = f2b(v.x); o.y = f2b(v.y); o.z = f2b(v.z); o.w = f2b(v.w);
    out[i] = o;
  }
}

// ---------- Wcomb = w_lin @ w_out (fp32), b_comb = w_lin@b_out + b_lin ----------
__global__ __launch_bounds__(256) void k_prepw(const float* __restrict__ w_lin, const float* __restrict__ w_out,
    const float* __restrict__ b_out, const float* __restrict__ b_lin,
    float* __restrict__ wcf, float* __restrict__ bc){
  int l = blockIdx.x, i = threadIdx.x;
  float s = 0.f;
  for (int j = 0; j < 256; ++j) s += w_lin[l*256 + j] * w_out[j*256 + i];
  wcf[l*256 + i] = s;
  __shared__ float red[256];
  red[i] = w_lin[l*256 + i] * b_out[i];
  __syncthreads();
  for (int off = 128; off > 0; off >>= 1){ if (i < off) red[i] += red[i + off]; __syncthreads(); }
  if (i == 0) bc[l] = red[0] + b_lin[l];
}

// ---------- fused QKV GEMM: qkv = X @ Wqkv^T, with q-softmax + k-stats epilogues ----------
// bn 0,1: q -> per-(row,head) softmax*scale (no-max, shift-invariant) -> qs
// bn 2,3: k -> qkv + per-column (max,sumexp) partials -> pm/ps
// bn 4,5: v -> qkv
__global__ __launch_bounds__(256, 3) void k_gemm_qkv(const u16* __restrict__ A, const u16* __restrict__ B,
    u16* __restrict__ qkv, u16* __restrict__ qs,
    float* __restrict__ pm, float* __restrict__ ps, int M){
  constexpr int K = 256, NT = 8;
  __shared__ __align__(16) u16 As[3][128*32];
  __shared__ __align__(16) u16 Bs[3][128*32];
  __shared__ float redm[2][2][64], reds[2][2][64];
  const int t = threadIdx.x;
  const int wave = t >> 6, lane = t & 63;
  const int bi = blockIdx.x;
  const int xk = bi & 7, bj = bi >> 3;
  const int bm = (xk + 8*(bj/6)) * 128;
  const int bn = bj % 6;
  const int srow = wave*32 + (lane>>2);
  const int skel = (((lane&3) ^ ((lane>>3)&3)) << 3);
  const u16* ag = A + (size_t)(bm + srow)*K + skel;
  const u16* bg = B + (size_t)(bn*128 + srow)*K + skel;
  const size_t rstep = (size_t)16*K;
  const int wr = (wave>>1)*64, wc4 = (wave&1)*64;
  const int fr = lane & 15;
  const int fkc = lane >> 4;
  const int koff = ((fkc ^ ((fr>>1)&3)) << 3);
  f32x4 acc[4][4] = {};
  #pragma unroll
  for (int pre = 0; pre < 2; ++pre){
    u16* asl = As[pre] + wave*1024; u16* bsl = Bs[pre] + wave*1024;
    const int k0 = pre*32;
    GLOAD_LDS16(ag + k0,         asl);
    GLOAD_LDS16(ag + rstep + k0, asl + 512);
    GLOAD_LDS16(bg + k0,         bsl);
    GLOAD_LDS16(bg + rstep + k0, bsl + 512);
  }
  #pragma unroll
  for (int it = 0; it < NT; ++it){
    const int cur = it % 3;
    if (it == NT-1) { asm volatile("s_waitcnt vmcnt(0)" ::: "memory"); }
    else            { asm volatile("s_waitcnt vmcnt(4)" ::: "memory"); }
    __builtin_amdgcn_s_barrier();
    __builtin_amdgcn_sched_barrier(0);
    short8 av[4], bv[4];
    #pragma unroll
    for (int m = 0; m < 4; ++m)
      av[m] = *(const short8*)&As[cur][(wr + m*16 + fr)*32 + koff];
    #pragma unroll
    for (int n = 0; n < 4; ++n)
      bv[n] = *(const short8*)&Bs[cur][(wc4 + n*16 + fr)*32 + koff];
    if (it + 2 < NT){
      const int nb = (it+2) % 3;
      u16* asl = As[nb] + wave*1024; u16* bsl = Bs[nb] + wave*1024;
      const int k0 = (it+2)*32;
      GLOAD_LDS16(ag + k0,         asl);
      GLOAD_LDS16(ag + rstep + k0, asl + 512);
      GLOAD_LDS16(bg + k0,         bsl);
      GLOAD_LDS16(bg + rstep + k0, bsl + 512);
    }
    __builtin_amdgcn_s_setprio(1);
    #pragma unroll
    for (int m = 0; m < 4; ++m)
      #pragma unroll
      for (int n = 0; n < 4; ++n)
        acc[m][n] = __builtin_amdgcn_mfma_f32_16x16x32_bf16(av[m], bv[n], acc[m][n], 0, 0, 0);
    __builtin_amdgcn_s_setprio(0);
  }
  const int orow0 = bm + wr + (lane>>4)*4;
  if (bn < 2){
    // q-softmax over 32 channels/head; shift-invariant -> skip max pass (|q| small)
    #pragma unroll
    for (int j = 0; j < 2; ++j){
      #pragma unroll
      for (int m = 0; m < 4; ++m)
        #pragma unroll
        for (int r = 0; r < 4; ++r){
          float e0 = __expf(acc[m][2*j][r]), e1 = __expf(acc[m][2*j+1][r]);
          float sum = e0 + e1;
          sum += __shfl_xor(sum, 1, 64);
          sum += __shfl_xor(sum, 2, 64);
          sum += __shfl_xor(sum, 4, 64);
          sum += __shfl_xor(sum, 8, 64);
          float sc = 0.17677669529663689f / sum;
          size_t base = (size_t)(orow0 + m*16 + r) * 256 + bn*128 + wc4 + j*32 + fr;
          qs[base]      = f2b(e0 * sc);
          qs[base + 16] = f2b(e1 * sc);
        }
    }
  } else {
    const int ocol0 = bn*128 + wc4 + fr;
    #pragma unroll
    for (int m = 0; m < 4; ++m)
      #pragma unroll
      for (int r = 0; r < 4; ++r){
        size_t base = (size_t)(orow0 + m*16 + r) * 768;
        #pragma unroll
        for (int n = 0; n < 4; ++n)
          qkv[base + ocol0 + n*16] = f2b(acc[m][n][r]);
      }
    if (bn < 4){
      #pragma unroll
      for (int n = 0; n < 4; ++n){
        float mx = -1e30f;
        #pragma unroll
        for (int m = 0; m < 4; ++m)
          #pragma unroll
          for (int r = 0; r < 4; ++r)
            mx = fmaxf(mx, rb(acc[m][n][r]));
        mx = fmaxf(mx, __shfl_xor(mx, 16, 64));
        mx = fmaxf(mx, __shfl_xor(mx, 32, 64));
        float sum = 0.f;
        #pragma unroll
        for (int m = 0; m < 4; ++m)
          #pragma unroll
          for (int r = 0; r < 4; ++r)
            sum += __expf(rb(acc[m][n][r]) - mx);
        sum += __shfl_xor(sum, 16, 64);
        sum += __shfl_xor(sum, 32, 64);
        if (lane < 16){
          redm[wave>>1][wave&1][n*16 + lane] = mx;
          reds[wave>>1][wave&1][n*16 + lane] = sum;
        }
      }
      __syncthreads();
      if (t < 128){
        int half = t >> 6, cc = t & 63;
        float ma = redm[0][half][cc], mb2 = redm[1][half][cc];
        float m2 = fmaxf(ma, mb2);
        float s2 = reds[0][half][cc]*__expf(ma - m2) + reds[1][half][cc]*__expf(mb2 - m2);
        int frame = bm / 9216, mrel = (bm % 9216) >> 7;
        size_t idx = ((size_t)frame*72 + mrel)*256 + (size_t)(bn-2)*128 + t;
        pm[idx] = m2; ps[idx] = s2;
      }
    }
  }
}

// ---------- generic MFMA GEMM (used for the output GEMM) ----------
template<int K>
__global__ __launch_bounds__(256, 3) void k_gemm_mfma(const u16* __restrict__ A, const u16* __restrict__ B,
    u16* __restrict__ Cb, float* __restrict__ Cf,
    const float* __restrict__ bias, const u16* __restrict__ residb,
    int M, int N, int NB, int frame_rows){
  __shared__ __align__(16) u16 As[3][128*32];
  __shared__ __align__(16) u16 Bs[3][128*32];
  const int t = threadIdx.x;
  const int wave = t >> 6, lane = t & 63;
  const int bi = blockIdx.x;
  const int xk = bi & 7, bj = bi >> 3;
  const int bm = (xk + 8*(bj/NB)) * 128, bn = (bj%NB) * 128;
  if (frame_rows > 0) B += (size_t)(bm / frame_rows) * N * K;
  const int srow = wave*32 + (lane>>2);
  const int skel = (((lane&3) ^ ((lane>>3)&3)) << 3);
  const u16* ag = A + (size_t)(bm + srow)*K + skel;
  const u16* bg = B + (size_t)(bn + srow)*K + skel;
  const size_t rstep = (size_t)16*K;
  const int wr = (wave>>1)*64, wc4 = (wave&1)*64;
  const int fr = lane & 15;
  const int fkc = lane >> 4;
  const int koff = ((fkc ^ ((fr>>1)&3)) << 3);
  constexpr int NT = K/32;
  f32x4 acc[4][4] = {};
  #pragma unroll
  for (int pre = 0; pre < 2; ++pre){
    u16* asl = As[pre] + wave*1024; u16* bsl = Bs[pre] + wave*1024;
    const int k0 = pre*32;
    GLOAD_LDS16(ag + k0,         asl);
    GLOAD_LDS16(ag + rstep + k0, asl + 512);
    GLOAD_LDS16(bg + k0,         bsl);
    GLOAD_LDS16(bg + rstep + k0, bsl + 512);
  }
  #pragma unroll
  for (int it = 0; it < NT; ++it){
    const int cur = it % 3;
    if (it == NT-1) { asm volatile("s_waitcnt vmcnt(0)" ::: "memory"); }
    else            { asm volatile("s_waitcnt vmcnt(4)" ::: "memory"); }
    __builtin_amdgcn_s_barrier();
    __builtin_amdgcn_sched_barrier(0);
    short8 av[4], bv[4];
    #pragma unroll
    for (int m = 0; m < 4; ++m)
      av[m] = *(const short8*)&As[cur][(wr + m*16 + fr)*32 + koff];
    #pragma unroll
    for (int n = 0; n < 4; ++n)
      bv[n] = *(const short8*)&Bs[cur][(wc4 + n*16 + fr)*32 + koff];
    if (it + 2 < NT){
      const int nb = (it+2) % 3;
      u16* asl = As[nb] + wave*1024; u16* bsl = Bs[nb] + wave*1024;
      const int k0 = (it+2)*32;
      GLOAD_LDS16(ag + k0,         asl);
      GLOAD_LDS16(ag + rstep + k0, asl + 512);
      GLOAD_LDS16(bg + k0,         bsl);
      GLOAD_LDS16(bg + rstep + k0, bsl + 512);
    }
    __builtin_amdgcn_s_setprio(1);
    #pragma unroll
    for (int m = 0; m < 4; ++m)
      #pragma unroll
      for (int n = 0; n < 4; ++n)
        acc[m][n] = __builtin_amdgcn_mfma_f32_16x16x32_bf16(av[m], bv[n], acc[m][n], 0, 0, 0);
    __builtin_amdgcn_s_setprio(0);
  }
  const int orow0 = bm + wr + (lane>>4)*4;
  const int ocol0 = bn + wc4 + fr;
  if (Cf){
    #pragma unroll
    for (int m = 0; m < 4; ++m)
      #pragma unroll
      for (int r = 0; r < 4; ++r){
        size_t base = (size_t)(orow0 + m*16 + r) * N;
        #pragma unroll
        for (int n = 0; n < 4; ++n){
          int col = ocol0 + n*16;
          Cf[base + col] = acc[m][n][r] + bias[col] + b2f(residb[base + col]);
        }
      }
  } else {
    #pragma unroll
    for (int m = 0; m < 4; ++m)
      #pragma unroll
      for (int r = 0; r < 4; ++r){
        size_t base = (size_t)(orow0 + m*16 + r) * N;
        #pragma unroll
        for (int n = 0; n < 4; ++n)
          Cb[base + ocol0 + n*16] = f2b(acc[m][n][r]);
      }
  }
}

// ---------- k softmax stats, pass 2: reduce 72 per-block partials ----------
__global__ __launch_bounds__(256) void k_kstats2(const float* __restrict__ pm, const float* __restrict__ ps,
    float* __restrict__ kmax, float* __restrict__ kiz){
  int frel = blockIdx.x, c = threadIdx.x;
  size_t b = (size_t)frel*72*256 + c;
  float m = -1e30f;
  #pragma unroll 8
  for (int s = 0; s < 72; ++s) m = fmaxf(m, pm[b + s*256]);
  float sum = 0.f;
  #pragma unroll 8
  for (int s = 0; s < 72; ++s) sum += ps[b + s*256] * __expf(pm[b + s*256] - m);
  kmax[frel*256 + c] = m;
  kiz [frel*256 + c] = 1.0f/sum;
}

// ---------- ctx partials: ctx[dd,e] += softmax_k[dd,n] * v[e,n] ----------
// Vectorized staging: thread loads short8 (8ch) of K and V per 64-token tile.
// Compute: register-blocked 4x4 per thread, tq splits tokens 16 each.
__global__ __launch_bounds__(256) void k_ctx(const u16* __restrict__ qkv,
    const float* __restrict__ kmax, const float* __restrict__ kiz, float* __restrict__ ctxp){
  const int h = blockIdx.x, frel = blockIdx.y, s = blockIdx.z;
  const int t = threadIdx.x;
  const int srow = t >> 2;            // staging row 0..63
  const int sch  = (t & 3) * 8;       // staging channel chunk
  const int tq = t >> 6;
  const int d0 = ((t >> 3) & 7) * 4;
  const int e0 = (t & 7) * 4;
  __shared__ float Ks[64*36];
  __shared__ float Vs[64*36];
  __shared__ float red[4][1024];
  const u16* kb = qkv + (size_t)frel * 9216 * 768 + 256 + h * 32;
  const u16* vb = kb + 256;
  // per-channel stats for this thread's 8 staging channels
  float4 mx0 = *(const float4*)&kmax[frel*256 + h*32 + sch];
  float4 mx1 = *(const float4*)&kmax[frel*256 + h*32 + sch + 4];
  float4 iz0 = *(const float4*)&kiz [frel*256 + h*32 + sch];
  float4 iz1 = *(const float4*)&kiz [frel*256 + h*32 + sch + 4];
  float mxv[8] = {mx0.x,mx0.y,mx0.z,mx0.w,mx1.x,mx1.y,mx1.z,mx1.w};
  float izv[8] = {iz0.x,iz0.y,iz0.z,iz0.w,iz1.x,iz1.y,iz1.z,iz1.w};
  float acc[4][4] = {};
  const int nend = (s + 1) * 576;
  for (int n0 = s * 576; n0 < nend; n0 += 64){
    __syncthreads();
    {
      size_t off = (size_t)(n0 + srow) * 768 + sch;
      short8 kv8 = *(const short8*)(kb + off);
      short8 vv8 = *(const short8*)(vb + off);
      float kf[8], vf[8];
      #pragma unroll
      for (int j = 0; j < 8; ++j){
        kf[j] = __expf(b2f((u16)kv8[j]) - mxv[j]) * izv[j];
        vf[j] = b2f((u16)vv8[j]);
      }
      float* kd = &Ks[srow*36 + sch];
      float* vd = &Vs[srow*36 + sch];
      *(float4*)(kd)     = *(float4*)&kf[0];
      *(float4*)(kd + 4) = *(float4*)&kf[4];
      *(float4*)(vd)     = *(float4*)&vf[0];
      *(float4*)(vd + 4) = *(float4*)&vf[4];
    }
    __syncthreads();
    #pragma unroll
    for (int q2 = 0; q2 < 16; ++q2){
      int nn = tq*16 + q2;
      float4 kk = *(const float4*)&Ks[nn*36 + d0];
      float4 vv = *(const float4*)&Vs[nn*36 + e0];
      acc[0][0] += kk.x*vv.x; acc[0][1] += kk.x*vv.y; acc[0][2] += kk.x*vv.z; acc[0][3] += kk.x*vv.w;
      acc[1][0] += kk.y*vv.x; acc[1][1] += kk.y*vv.y; acc[1][2] += kk.y*vv.z; acc[1][3] += kk.y*vv.w;
      acc[2][0] += kk.z*vv.x; acc[2][1] += kk.z*vv.y; acc[2][2] += kk.z*vv.z; acc[2][3] += kk.z*vv.w;
      acc[3][0] += kk.w*vv.x; acc[3][1] += kk.w*vv.y; acc[3][2] += kk.w*vv.z; acc[3][3] += kk.w*vv.w;
    }
  }
  __syncthreads();
  #pragma unroll
  for (int i = 0; i < 4; ++i)
    #pragma unroll
    for (int j = 0; j < 4; ++j)
      red[tq][(d0+i)*32 + e0 + j] = acc[i][j];
  __syncthreads();
  float* cb = ctxp + (((size_t)frel*16 + s)*8 + h)*1024;
  for (int idx = t; idx < 1024; idx += 256)
    cb[idx] = red[0][idx] + red[1][idx] + red[2][idx] + red[3][idx];
}

__global__ void k_ctxred(const float* __restrict__ ctxp, float* __restrict__ ctx){
  int frel = blockIdx.x, t = threadIdx.x;
  for (int i = t; i < 8192; i += 256){
    float s = 0.f;
    #pragma unroll
    for (int q = 0; q < 16; ++q) s += ctxp[((size_t)frel*16 + q)*8192 + i];
    ctx[(size_t)frel*8192 + i] = s;
  }
}

// ---------- Weff_f[l, h*32+dd] = sum_e ctx_f[h][dd,e] * Wcomb[l, h*32+e] ----------
__global__ __launch_bounds__(256) void k_weff(const float* __restrict__ ctx, const float* __restrict__ wcf,
    u16* __restrict__ weff){
  int l = blockIdx.x, frel = blockIdx.y, t = threadIdx.x;
  int h = t >> 5, dd = t & 31;
  const float* cr = ctx + (size_t)frel*8192 + h*1024 + dd*32;
  const float* wr = wcf + (size_t)l*256 + h*32;
  float s = 0.f;
  #pragma unroll
  for (int e = 0; e < 32; ++e) s += cr[e] * wr[e];
  weff[((size_t)frel*256 + l)*256 + t] = f2b(s);
}

extern "C" void kernel_launch(void* const* d_in, const int* in_sizes, int n_in,
                              void* d_out, int out_size, void* d_ws, size_t ws_size,
                              hipStream_t stream){
  const float* x     = (const float*)d_in[0];
  const float* w_qkv = (const float*)d_in[1];
  const float* w_out = (const float*)d_in[2];
  const float* b_out = (const float*)d_in[3];
  const float* w_lin = (const float*)d_in[4];
  const float* b_lin = (const float*)d_in[5];
  float* out = (float*)d_out;

  char* p = (char*)d_ws;
  u16*   wqb   = (u16*)p;   p += (size_t)768*256*2;
  float* wcf   = (float*)p; p += (size_t)256*256*4;
  float* bc    = (float*)p; p += 256*4;
  float* kmaxb = (float*)p; p += 8*256*4;
  float* kizb  = (float*)p; p += 8*256*4;
  float* pmb   = (float*)p; p += (size_t)8*72*256*4;
  float* psb   = (float*)p; p += (size_t)8*72*256*4;
  float* ctxpb = (float*)p; p += (size_t)8*16*8192*4;
  float* ctxb  = (float*)p; p += (size_t)8*8192*4;
  u16*   weffb = (u16*)p;   p += (size_t)8*256*256*2;
  size_t fixed = (size_t)(p - (char*)d_ws);
  size_t per_frame = (size_t)9216*256*2 + (size_t)9216*768*2 + (size_t)9216*256*2;
  int chunk = (ws_size >= fixed + 8*per_frame) ? 8 : 1;
  u16* xb   = (u16*)p;
  u16* qkvb = xb   + (size_t)chunk*9216*256;
  u16* qsmb = qkvb + (size_t)chunk*9216*768;

  // weight prep (once)
  hipLaunchKernelGGL(k_cvt, dim3(192), dim3(256), 0, stream, (const float4*)w_qkv, (ushort4*)wqb, 49152);
  hipLaunchKernelGGL(k_prepw, dim3(256), dim3(256), 0, stream, w_lin, w_out, b_out, b_lin, wcf, bc);

  for (int f0 = 0; f0 < 8; f0 += chunk){
    const float* xc = x  + (size_t)f0*9216*256;
    float*       oc = out + (size_t)f0*9216*256;
    const int M = chunk * 9216;
    const int n4 = M * 256 / 4;
    hipLaunchKernelGGL(k_cvt, dim3((n4 + 255)/256), dim3(256), 0, stream, (const float4*)xc, (ushort4*)xb, n4);
    hipLaunchKernelGGL(k_gemm_qkv, dim3((M/128)*6), dim3(256), 0, stream,
                       xb, wqb, qkvb, qsmb, pmb, psb, M);
    hipLaunchKernelGGL(k_kstats2, dim3(chunk), dim3(256), 0, stream, pmb, psb, kmaxb, kizb);
    hipLaunchKernelGGL(k_ctx, dim3(8, chunk, 16), dim3(256), 0, stream, qkvb, kmaxb, kizb, ctxpb);
    hipLaunchKernelGGL(k_ctxred, dim3(chunk), dim3(256), 0, stream, ctxpb, ctxb);
    hipLaunchKernelGGL(k_weff, dim3(256, chunk), dim3(256), 0, stream,
                       ctxb, wcf, weffb + (size_t)f0*256*256);
    hipLaunchKernelGGL((k_gemm_mfma<256>), dim3((M/128)*2), dim3(256), 0, stream,
                       qsmb, weffb + (size_t)f0*256*256, (u16*)nullptr, oc, bc, xb,
                       M, 256, 2, (chunk == 8) ? 9216 : 0);
  }
}

// Round 11
// 184.229 us; speedup vs baseline: 6.5503x; 1.0714x over previous
//
#include <hip/hip_runtime.h>

using u16 = unsigned short;
typedef __attribute__((ext_vector_type(8))) short short8;
typedef __attribute__((ext_vector_type(4))) float f32x4;

__device__ __forceinline__ float b2f(u16 u){ union{unsigned u; float f;} c; c.u = ((unsigned)u) << 16; return c.f; }
__device__ __forceinline__ u16 f2b(float f){
  union{float f; unsigned u;} c; c.f = f;
  unsigned r = 0x7fffu + ((c.u >> 16) & 1u);
  return (u16)((c.u + r) >> 16);
}

#define GLOAD_LDS16(g, l) __builtin_amdgcn_global_load_lds( \
  (const __attribute__((address_space(1))) unsigned int*)(g), \
  (__attribute__((address_space(3))) unsigned int*)(l), 16, 0, 0)

// ---------- f32 -> bf16 convert, 4/thread ----------
__global__ void k_cvt(const float4* __restrict__ in, ushort4* __restrict__ out, int n4){
  int i = blockIdx.x * 256 + threadIdx.x;
  if (i < n4){
    float4 v = in[i];
    ushort4 o; o.x = f2b(v.x); o.y = f2b(v.y); o.z = f2b(v.z); o.w = f2b(v.w);
    out[i] = o;
  }
}

// ---------- Wcomb = w_lin @ w_out (fp32), b_comb = w_lin@b_out + b_lin ----------
__global__ __launch_bounds__(256) void k_prepw(const float* __restrict__ w_lin, const float* __restrict__ w_out,
    const float* __restrict__ b_out, const float* __restrict__ b_lin,
    float* __restrict__ wcf, float* __restrict__ bc){
  int l = blockIdx.x, i = threadIdx.x;
  float s = 0.f;
  for (int j = 0; j < 256; ++j) s += w_lin[l*256 + j] * w_out[j*256 + i];
  wcf[l*256 + i] = s;
  __shared__ float red[256];
  red[i] = w_lin[l*256 + i] * b_out[i];
  __syncthreads();
  for (int off = 128; off > 0; off >>= 1){ if (i < off) red[i] += red[i + off]; __syncthreads(); }
  if (i == 0) bc[l] = red[0] + b_lin[l];
}

// ---------- fused QKV GEMM with LDS-transpose epilogues ----------
// bn 0,1: q -> (store phase) per-head no-max softmax*scale -> qs [M][256]
// bn 2,3: ek = exp(k) -> ekp head-major [8][M][32]  (unnormalized; 1/Z folded later)
// bn 4,5: v -> vp head-major [8][M][32]
__global__ __launch_bounds__(256, 3) void k_gemm_qkv(const u16* __restrict__ A, const u16* __restrict__ B,
    u16* __restrict__ qs, u16* __restrict__ ekp, u16* __restrict__ vp, int M){
  constexpr int K = 256, NT = 8;
  __shared__ __align__(16) u16 pool[24576];   // staging 48KB; epilogue overlays cmat[128][136]
  u16* As = pool;            // 3 x 4096
  u16* Bs = pool + 12288;    // 3 x 4096
  const int t = threadIdx.x;
  const int wave = t >> 6, lane = t & 63;
  const int bi = blockIdx.x;
  const int xk = bi & 7, bj = bi >> 3;
  const int bm = (xk + 8*(bj/6)) * 128;
  const int bn = bj % 6;
  const int srow = wave*32 + (lane>>2);
  const int skel = (((lane&3) ^ ((lane>>3)&3)) << 3);
  const u16* ag = A + (size_t)(bm + srow)*K + skel;
  const u16* bg = B + (size_t)(bn*128 + srow)*K + skel;
  const size_t rstep = (size_t)16*K;
  const int wr = (wave>>1)*64, wc4 = (wave&1)*64;
  const int fr = lane & 15;
  const int fkc = lane >> 4;
  const int koff = ((fkc ^ ((fr>>1)&3)) << 3);
  f32x4 acc[4][4] = {};
  #pragma unroll
  for (int pre = 0; pre < 2; ++pre){
    u16* asl = As + pre*4096 + wave*1024; u16* bsl = Bs + pre*4096 + wave*1024;
    const int k0 = pre*32;
    GLOAD_LDS16(ag + k0,         asl);
    GLOAD_LDS16(ag + rstep + k0, asl + 512);
    GLOAD_LDS16(bg + k0,         bsl);
    GLOAD_LDS16(bg + rstep + k0, bsl + 512);
  }
  #pragma unroll
  for (int it = 0; it < NT; ++it){
    const int cur = it % 3;
    if (it == NT-1) { asm volatile("s_waitcnt vmcnt(0)" ::: "memory"); }
    else            { asm volatile("s_waitcnt vmcnt(4)" ::: "memory"); }
    __builtin_amdgcn_s_barrier();
    __builtin_amdgcn_sched_barrier(0);
    short8 av[4], bv[4];
    #pragma unroll
    for (int m = 0; m < 4; ++m)
      av[m] = *(const short8*)&As[cur*4096 + (wr + m*16 + fr)*32 + koff];
    #pragma unroll
    for (int n = 0; n < 4; ++n)
      bv[n] = *(const short8*)&Bs[cur*4096 + (wc4 + n*16 + fr)*32 + koff];
    if (it + 2 < NT){
      const int nb = (it+2) % 3;
      u16* asl = As + nb*4096 + wave*1024; u16* bsl = Bs + nb*4096 + wave*1024;
      const int k0 = (it+2)*32;
      GLOAD_LDS16(ag + k0,         asl);
      GLOAD_LDS16(ag + rstep + k0, asl + 512);
      GLOAD_LDS16(bg + k0,         bsl);
      GLOAD_LDS16(bg + rstep + k0, bsl + 512);
    }
    __builtin_amdgcn_s_setprio(1);
    #pragma unroll
    for (int m = 0; m < 4; ++m)
      #pragma unroll
      for (int n = 0; n < 4; ++n)
        acc[m][n] = __builtin_amdgcn_mfma_f32_16x16x32_bf16(av[m], bv[n], acc[m][n], 0, 0, 0);
    __builtin_amdgcn_s_setprio(0);
  }
  // ---- epilogue: acc -> cmat (bf16) -> coalesced stores ----
  __syncthreads();               // all waves done reading staging LDS
  u16* cmat = pool;              // [128][136], 16B-aligned rows
  const int lr0 = wr + (lane>>4)*4;
  const bool isK = (bn == 2 || bn == 3);
  #pragma unroll
  for (int m = 0; m < 4; ++m)
    #pragma unroll
    for (int n = 0; n < 4; ++n)
      #pragma unroll
      for (int r = 0; r < 4; ++r){
        float v = acc[m][n][r];
        if (isK) v = __expf(v);
        cmat[(lr0 + m*16 + r)*136 + wc4 + n*16 + fr] = f2b(v);
      }
  __syncthreads();
  if (bn < 2){
    // q: row t>>1, 64-col half (t&1) = 2 complete heads; in-thread softmax, no shuffles
    const int row = t >> 1, co = (t & 1) * 64;
    #pragma unroll
    for (int hh = 0; hh < 2; ++hh){
      float f[32];
      #pragma unroll
      for (int c4 = 0; c4 < 4; ++c4){
        short8 w = *(const short8*)&cmat[row*136 + co + hh*32 + c4*8];
        #pragma unroll
        for (int k2 = 0; k2 < 8; ++k2) f[c4*8+k2] = b2f((u16)w[k2]);
      }
      float sum = 0.f;
      #pragma unroll
      for (int i2 = 0; i2 < 32; ++i2){ float e = __expf(f[i2]); f[i2] = e; sum += e; }
      float sc = 0.17677669529663689f / sum;
      #pragma unroll
      for (int c4 = 0; c4 < 4; ++c4){
        short8 o;
        #pragma unroll
        for (int k2 = 0; k2 < 8; ++k2) o[k2] = (short)f2b(f[c4*8+k2] * sc);
        *(short8*)&qs[(size_t)(bm+row)*256 + bn*128 + co + hh*32 + c4*8] = o;
      }
    }
  } else {
    // k/v: head-major planes; wave w handles head_local w, token = g and g+64
    u16* plane = isK ? ekp : vp;
    const int hl = t >> 6, g = t & 63;
    const int head = ((bn & 1) ? 4 : 0) + hl;
    #pragma unroll
    for (int tp = 0; tp < 2; ++tp){
      const int tok = g + tp*64;
      #pragma unroll
      for (int j = 0; j < 4; ++j){
        short8 w = *(const short8*)&cmat[tok*136 + hl*32 + j*8];
        *(short8*)&plane[((size_t)head*M + bm + tok)*32 + j*8] = w;
      }
    }
  }
}

// ---------- output GEMM: out = qs @ Weff_f^T + bc + resid, LDS-transpose epilogue ----------
__global__ __launch_bounds__(256, 3) void k_gemm_out(const u16* __restrict__ A, const u16* __restrict__ B,
    float* __restrict__ Cf, const float* __restrict__ bias, const u16* __restrict__ residb,
    int M, int NB, int frame_rows){
  constexpr int K = 256, N = 256, NT = 8;
  __shared__ __align__(16) u16 pool[24576];
  u16* As = pool;
  u16* Bs = pool + 12288;
  const int t = threadIdx.x;
  const int wave = t >> 6, lane = t & 63;
  const int bi = blockIdx.x;
  const int xk = bi & 7, bj = bi >> 3;
  const int bm = (xk + 8*(bj/NB)) * 128, bn = (bj%NB) * 128;
  if (frame_rows > 0) B += (size_t)(bm / frame_rows) * N * K;
  const int srow = wave*32 + (lane>>2);
  const int skel = (((lane&3) ^ ((lane>>3)&3)) << 3);
  const u16* ag = A + (size_t)(bm + srow)*K + skel;
  const u16* bg = B + (size_t)(bn + srow)*K + skel;
  const size_t rstep = (size_t)16*K;
  const int wr = (wave>>1)*64, wc4 = (wave&1)*64;
  const int fr = lane & 15;
  const int fkc = lane >> 4;
  const int koff = ((fkc ^ ((fr>>1)&3)) << 3);
  f32x4 acc[4][4] = {};
  #pragma unroll
  for (int pre = 0; pre < 2; ++pre){
    u16* asl = As + pre*4096 + wave*1024; u16* bsl = Bs + pre*4096 + wave*1024;
    const int k0 = pre*32;
    GLOAD_LDS16(ag + k0,         asl);
    GLOAD_LDS16(ag + rstep + k0, asl + 512);
    GLOAD_LDS16(bg + k0,         bsl);
    GLOAD_LDS16(bg + rstep + k0, bsl + 512);
  }
  #pragma unroll
  for (int it = 0; it < NT; ++it){
    const int cur = it % 3;
    if (it == NT-1) { asm volatile("s_waitcnt vmcnt(0)" ::: "memory"); }
    else            { asm volatile("s_waitcnt vmcnt(4)" ::: "memory"); }
    __builtin_amdgcn_s_barrier();
    __builtin_amdgcn_sched_barrier(0);
    short8 av[4], bv[4];
    #pragma unroll
    for (int m = 0; m < 4; ++m)
      av[m] = *(const short8*)&As[cur*4096 + (wr + m*16 + fr)*32 + koff];
    #pragma unroll
    for (int n = 0; n < 4; ++n)
      bv[n] = *(const short8*)&Bs[cur*4096 + (wc4 + n*16 + fr)*32 + koff];
    if (it + 2 < NT){
      const int nb = (it+2) % 3;
      u16* asl = As + nb*4096 + wave*1024; u16* bsl = Bs + nb*4096 + wave*1024;
      const int k0 = (it+2)*32;
      GLOAD_LDS16(ag + k0,         asl);
      GLOAD_LDS16(ag + rstep + k0, asl + 512);
      GLOAD_LDS16(bg + k0,         bsl);
      GLOAD_LDS16(bg + rstep + k0, bsl + 512);
    }
    __builtin_amdgcn_s_setprio(1);
    #pragma unroll
    for (int m = 0; m < 4; ++m)
      #pragma unroll
      for (int n = 0; n < 4; ++n)
        acc[m][n] = __builtin_amdgcn_mfma_f32_16x16x32_bf16(av[m], bv[n], acc[m][n], 0, 0, 0);
    __builtin_amdgcn_s_setprio(0);
  }
  // ---- epilogue: two 64-row halves through cmatf[64][132] ----
  __syncthreads();
  float* cmatf = (float*)pool;
  const int lr0 = (lane>>4)*4;       // local within half
  float biasr[32];
  {
    const int c0 = bn + (t&3)*32;
    #pragma unroll
    for (int c4 = 0; c4 < 8; ++c4)
      *(float4*)&biasr[c4*4] = *(const float4*)&bias[c0 + c4*4];
  }
  #pragma unroll
  for (int half = 0; half < 2; ++half){
    if ((wr >> 6) == half){
      #pragma unroll
      for (int m = 0; m < 4; ++m)
        #pragma unroll
        for (int n = 0; n < 4; ++n)
          #pragma unroll
          for (int r = 0; r < 4; ++r)
            cmatf[(lr0 + m*16 + r)*132 + wc4 + n*16 + fr] = acc[m][n][r];
    }
    __syncthreads();
    {
      const int row = t >> 2, seg = (t & 3) * 32;
      const int gr = bm + half*64 + row;
      const size_t gbase = (size_t)gr*256 + bn + seg;
      float v[32];
      #pragma unroll
      for (int c4 = 0; c4 < 8; ++c4)
        *(float4*)&v[c4*4] = *(const float4*)&cmatf[row*132 + seg + c4*4];
      #pragma unroll
      for (int c4 = 0; c4 < 4; ++c4){
        short8 rr = *(const short8*)&residb[gbase + c4*8];
        #pragma unroll
        for (int k2 = 0; k2 < 8; ++k2)
          v[c4*8+k2] += biasr[c4*8+k2] + b2f((u16)rr[k2]);
      }
      #pragma unroll
      for (int c4 = 0; c4 < 8; ++c4)
        *(float4*)&Cf[gbase + c4*4] = *(float4*)&v[c4*4];
    }
    __syncthreads();
  }
}

// ---------- ctx partials (unnormalized): ctx[dd,e] += ek[n,dd]*v[n,e]; z[dd] += ek[n,dd] ----------
__global__ __launch_bounds__(256) void k_ctx(const u16* __restrict__ ekp, const u16* __restrict__ vp,
    float* __restrict__ ctxp, float* __restrict__ zp, int M){
  const int h = blockIdx.x, frel = blockIdx.y, sblk = blockIdx.z;
  const int t = threadIdx.x;
  const int srow = t >> 2;            // staging row 0..63
  const int sch  = (t & 3) * 8;       // staging channel chunk
  const int tq = t >> 6;
  const int d0 = ((t >> 3) & 7) * 4;
  const int e0 = (t & 7) * 4;
  __shared__ float Ks[64*36];
  __shared__ float Vs[64*36];
  __shared__ float red[4][1024];
  const u16* kb = ekp + ((size_t)h*M + (size_t)frel*9216)*32;
  const u16* vb = vp  + ((size_t)h*M + (size_t)frel*9216)*32;
  float acc[4][4] = {};
  float z[8] = {};
  const int nend = (sblk + 1) * 576;
  for (int n0 = sblk * 576; n0 < nend; n0 += 64){
    __syncthreads();
    {
      size_t off = (size_t)(n0 + srow) * 32 + sch;
      short8 kv8 = *(const short8*)(kb + off);
      short8 vv8 = *(const short8*)(vb + off);
      float kf[8], vf[8];
      #pragma unroll
      for (int j = 0; j < 8; ++j){
        kf[j] = b2f((u16)kv8[j]);
        vf[j] = b2f((u16)vv8[j]);
        z[j] += kf[j];
      }
      float* kd = &Ks[srow*36 + sch];
      float* vd = &Vs[srow*36 + sch];
      *(float4*)(kd)     = *(float4*)&kf[0];
      *(float4*)(kd + 4) = *(float4*)&kf[4];
      *(float4*)(vd)     = *(float4*)&vf[0];
      *(float4*)(vd + 4) = *(float4*)&vf[4];
    }
    __syncthreads();
    #pragma unroll
    for (int q2 = 0; q2 < 16; ++q2){
      int nn = tq*16 + q2;
      float4 kk = *(const float4*)&Ks[nn*36 + d0];
      float4 vv = *(const float4*)&Vs[nn*36 + e0];
      acc[0][0] += kk.x*vv.x; acc[0][1] += kk.x*vv.y; acc[0][2] += kk.x*vv.z; acc[0][3] += kk.x*vv.w;
      acc[1][0] += kk.y*vv.x; acc[1][1] += kk.y*vv.y; acc[1][2] += kk.y*vv.z; acc[1][3] += kk.y*vv.w;
      acc[2][0] += kk.z*vv.x; acc[2][1] += kk.z*vv.y; acc[2][2] += kk.z*vv.z; acc[2][3] += kk.z*vv.w;
      acc[3][0] += kk.w*vv.x; acc[3][1] += kk.w*vv.y; acc[3][2] += kk.w*vv.z; acc[3][3] += kk.w*vv.w;
    }
  }
  __syncthreads();
  #pragma unroll
  for (int i = 0; i < 4; ++i)
    #pragma unroll
    for (int j = 0; j < 4; ++j)
      red[tq][(d0+i)*32 + e0 + j] = acc[i][j];
  __syncthreads();
  float* cb = ctxp + (((size_t)frel*16 + sblk)*8 + h)*1024;
  for (int idx = t; idx < 1024; idx += 256)
    cb[idx] = red[0][idx] + red[1][idx] + red[2][idx] + red[3][idx];
  __syncthreads();
  float* zr = (float*)red;
  #pragma unroll
  for (int j = 0; j < 8; ++j) zr[srow*32 + sch + j] = z[j];
  __syncthreads();
  if (t < 32){
    float s = 0.f;
    #pragma unroll 8
    for (int r2 = 0; r2 < 64; ++r2) s += zr[r2*32 + t];
    zp[(((size_t)frel*16 + sblk)*8 + h)*32 + t] = s;
  }
}

// ---------- reduce splits + apply 1/Z: ctx[f][h] scaled ----------
__global__ __launch_bounds__(256) void k_ctxred(const float* __restrict__ ctxp, const float* __restrict__ zp,
    float* __restrict__ ctx){
  const int h = blockIdx.x, frel = blockIdx.y;
  const int t = threadIdx.x;
  __shared__ float izs[32];
  if (t < 32){
    float zt = 0.f;
    #pragma unroll
    for (int q = 0; q < 16; ++q) zt += zp[(((size_t)frel*16 + q)*8 + h)*32 + t];
    izs[t] = 1.0f / zt;
  }
  __syncthreads();
  for (int idx = t; idx < 1024; idx += 256){
    float s = 0.f;
    #pragma unroll
    for (int q = 0; q < 16; ++q) s += ctxp[(((size_t)frel*16 + q)*8 + h)*1024 + idx];
    ctx[(size_t)frel*8192 + h*1024 + idx] = s * izs[idx >> 5];
  }
}

// ---------- Weff_f[l, h*32+dd] = sum_e ctx_f[h][dd,e] * Wcomb[l, h*32+e] ----------
__global__ __launch_bounds__(256) void k_weff(const float* __restrict__ ctx, const float* __restrict__ wcf,
    u16* __restrict__ weff){
  int l = blockIdx.x, frel = blockIdx.y, t = threadIdx.x;
  int h = t >> 5, dd = t & 31;
  const float* cr = ctx + (size_t)frel*8192 + h*1024 + dd*32;
  const float* wr = wcf + (size_t)l*256 + h*32;
  float s = 0.f;
  #pragma unroll
  for (int e = 0; e < 32; ++e) s += cr[e] * wr[e];
  weff[((size_t)frel*256 + l)*256 + t] = f2b(s);
}

extern "C" void kernel_launch(void* const* d_in, const int* in_sizes, int n_in,
                              void* d_out, int out_size, void* d_ws, size_t ws_size,
                              hipStream_t stream){
  const float* x     = (const float*)d_in[0];
  const float* w_qkv = (const float*)d_in[1];
  const float* w_out = (const float*)d_in[2];
  const float* b_out = (const float*)d_in[3];
  const float* w_lin = (const float*)d_in[4];
  const float* b_lin = (const float*)d_in[5];
  float* out = (float*)d_out;

  char* p = (char*)d_ws;
  u16*   wqb   = (u16*)p;   p += (size_t)768*256*2;
  float* wcf   = (float*)p; p += (size_t)256*256*4;
  float* bc    = (float*)p; p += 256*4;
  float* zpb   = (float*)p; p += (size_t)8*16*8*32*4;
  float* ctxpb = (float*)p; p += (size_t)8*16*8192*4;
  float* ctxb  = (float*)p; p += (size_t)8*8192*4;
  u16*   weffb = (u16*)p;   p += (size_t)8*256*256*2;
  size_t fixed = (size_t)(p - (char*)d_ws);
  size_t per_frame = (size_t)4 * 9216*256*2;   // xb + qs + ek + v
  int chunk = (ws_size >= fixed + 8*per_frame) ? 8 : 1;
  u16* xb  = (u16*)p;
  u16* qsb = xb  + (size_t)chunk*9216*256;
  u16* ekp = qsb + (size_t)chunk*9216*256;
  u16* vpb = ekp + (size_t)chunk*9216*256;

  // weight prep (once)
  hipLaunchKernelGGL(k_cvt, dim3(192), dim3(256), 0, stream, (const float4*)w_qkv, (ushort4*)wqb, 49152);
  hipLaunchKernelGGL(k_prepw, dim3(256), dim3(256), 0, stream, w_lin, w_out, b_out, b_lin, wcf, bc);

  for (int f0 = 0; f0 < 8; f0 += chunk){
    const float* xc = x  + (size_t)f0*9216*256;
    float*       oc = out + (size_t)f0*9216*256;
    const int M = chunk * 9216;
    const int n4 = M * 256 / 4;
    hipLaunchKernelGGL(k_cvt, dim3((n4 + 255)/256), dim3(256), 0, stream, (const float4*)xc, (ushort4*)xb, n4);
    hipLaunchKernelGGL(k_gemm_qkv, dim3((M/128)*6), dim3(256), 0, stream,
                       xb, wqb, qsb, ekp, vpb, M);
    hipLaunchKernelGGL(k_ctx, dim3(8, chunk, 16), dim3(256), 0, stream, ekp, vpb, ctxpb, zpb, M);
    hipLaunchKernelGGL(k_ctxred, dim3(8, chunk), dim3(256), 0, stream, ctxpb, zpb, ctxb);
    hipLaunchKernelGGL(k_weff, dim3(256, chunk), dim3(256), 0, stream,
                       ctxb, wcf, weffb + (size_t)f0*256*256);
    hipLaunchKernelGGL(k_gemm_out, dim3((M/128)*2), dim3(256), 0, stream,
                       qsb, weffb + (size_t)f0*256*256, oc, bc, xb,
                       M, 2, (chunk == 8) ? 9216 : 0);
  }
}

// Round 12
// 150.842 us; speedup vs baseline: 8.0001x; 1.2213x over previous
//
#include <hip/hip_runtime.h>

using u16 = unsigned short;
typedef __attribute__((ext_vector_type(8))) short short8;
typedef __attribute__((ext_vector_type(4))) float f32x4;

__device__ __forceinline__ float b2f(u16 u){ union{unsigned u; float f;} c; c.u = ((unsigned)u) << 16; return c.f; }
__device__ __forceinline__ u16 f2b(float f){
  union{float f; unsigned u;} c; c.f = f;
  unsigned r = 0x7fffu + ((c.u >> 16) & 1u);
  return (u16)((c.u + r) >> 16);
}

#define GLOAD_LDS16(g, l) __builtin_amdgcn_global_load_lds( \
  (const __attribute__((address_space(1))) unsigned int*)(g), \
  (__attribute__((address_space(3))) unsigned int*)(l), 16, 0, 0)

// ---------- f32 -> bf16 convert, 4/thread ----------
__global__ void k_cvt(const float4* __restrict__ in, ushort4* __restrict__ out, int n4){
  int i = blockIdx.x * 256 + threadIdx.x;
  if (i < n4){
    float4 v = in[i];
    ushort4 o; o.x = f2b(v.x); o.y = f2b(v.y); o.z = f2b(v.z); o.w = f2b(v.w);
    out[i] = o;
  }
}

// ---------- Wqkv convert + row permute: [q(256)][k01|v01][k23|v23][k45|v45][k67|v67] ----------
__global__ __launch_bounds__(256) void k_cvtw(const float* __restrict__ w, u16* __restrict__ out){
  int r = blockIdx.x, c = threadIdx.x;
  int src;
  if (r < 256) src = r;
  else { int g = r - 256, p4 = g >> 7, o = g & 127;
         src = (o < 64) ? 256 + p4*64 + o : 512 + p4*64 + (o - 64); }
  out[r*256 + c] = f2b(w[src*256 + c]);
}

// ---------- Wcomb = w_lin @ w_out (fp32), b_comb = w_lin@b_out + b_lin ----------
__global__ __launch_bounds__(256) void k_prepw(const float* __restrict__ w_lin, const float* __restrict__ w_out,
    const float* __restrict__ b_out, const float* __restrict__ b_lin,
    float* __restrict__ wcf, float* __restrict__ bc){
  int l = blockIdx.x, i = threadIdx.x;
  float s = 0.f;
  for (int j = 0; j < 256; ++j) s += w_lin[l*256 + j] * w_out[j*256 + i];
  wcf[l*256 + i] = s;
  __shared__ float red[256];
  red[i] = w_lin[l*256 + i] * b_out[i];
  __syncthreads();
  for (int off = 128; off > 0; off >>= 1){ if (i < off) red[i] += red[i + off]; __syncthreads(); }
  if (i == 0) bc[l] = red[0] + b_lin[l];
}

// ---------- fused QKV GEMM ----------
// bn 0,1: q -> LDS transpose -> per-head no-max softmax*scale -> qs [M][256]
// bn 2..5: ek|v for 2 heads -> transposed LDS tiles -> in-epilogue MFMA ctx+Z partials
__global__ __launch_bounds__(256, 3) void k_gemm_qkv(const u16* __restrict__ A, const u16* __restrict__ B,
    u16* __restrict__ qs, float* __restrict__ ctxp, float* __restrict__ zp, int M){
  constexpr int K = 256, NT = 8;
  __shared__ __align__(16) u16 pool[24576];   // staging 48KB; epilogue overlays
  u16* As = pool;            // 3 x 4096
  u16* Bs = pool + 12288;    // 3 x 4096
  const int t = threadIdx.x;
  const int wave = t >> 6, lane = t & 63;
  const int bi = blockIdx.x;
  const int xk = bi & 7, bj = bi >> 3;
  const int bm = (xk + 8*(bj/6)) * 128;
  const int bn = bj % 6;
  const int srow = wave*32 + (lane>>2);
  const int skel = (((lane&3) ^ ((lane>>3)&3)) << 3);
  const u16* ag = A + (size_t)(bm + srow)*K + skel;
  const u16* bg = B + (size_t)(bn*128 + srow)*K + skel;
  const size_t rstep = (size_t)16*K;
  const int wr = (wave>>1)*64, wc4 = (wave&1)*64;
  const int fr = lane & 15;
  const int fkc = lane >> 4;
  const int koff = ((fkc ^ ((fr>>1)&3)) << 3);
  f32x4 acc[4][4] = {};
  #pragma unroll
  for (int pre = 0; pre < 2; ++pre){
    u16* asl = As + pre*4096 + wave*1024; u16* bsl = Bs + pre*4096 + wave*1024;
    const int k0 = pre*32;
    GLOAD_LDS16(ag + k0,         asl);
    GLOAD_LDS16(ag + rstep + k0, asl + 512);
    GLOAD_LDS16(bg + k0,         bsl);
    GLOAD_LDS16(bg + rstep + k0, bsl + 512);
  }
  #pragma unroll
  for (int it = 0; it < NT; ++it){
    const int cur = it % 3;
    if (it == NT-1) { asm volatile("s_waitcnt vmcnt(0)" ::: "memory"); }
    else            { asm volatile("s_waitcnt vmcnt(4)" ::: "memory"); }
    __builtin_amdgcn_s_barrier();
    __builtin_amdgcn_sched_barrier(0);
    short8 av[4], bv[4];
    #pragma unroll
    for (int m = 0; m < 4; ++m)
      av[m] = *(const short8*)&As[cur*4096 + (wr + m*16 + fr)*32 + koff];
    #pragma unroll
    for (int n = 0; n < 4; ++n)
      bv[n] = *(const short8*)&Bs[cur*4096 + (wc4 + n*16 + fr)*32 + koff];
    if (it + 2 < NT){
      const int nb = (it+2) % 3;
      u16* asl = As + nb*4096 + wave*1024; u16* bsl = Bs + nb*4096 + wave*1024;
      const int k0 = (it+2)*32;
      GLOAD_LDS16(ag + k0,         asl);
      GLOAD_LDS16(ag + rstep + k0, asl + 512);
      GLOAD_LDS16(bg + k0,         bsl);
      GLOAD_LDS16(bg + rstep + k0, bsl + 512);
    }
    __builtin_amdgcn_s_setprio(1);
    #pragma unroll
    for (int m = 0; m < 4; ++m)
      #pragma unroll
      for (int n = 0; n < 4; ++n)
        acc[m][n] = __builtin_amdgcn_mfma_f32_16x16x32_bf16(av[m], bv[n], acc[m][n], 0, 0, 0);
    __builtin_amdgcn_s_setprio(0);
  }
  __syncthreads();               // all waves done reading staging LDS
  const int lr0 = wr + (lane>>4)*4;
  if (bn < 2){
    // q: acc -> cmat[128][136] -> per-row-head in-thread softmax (no-max), coalesced qs stores
    u16* cmat = pool;
    #pragma unroll
    for (int m = 0; m < 4; ++m)
      #pragma unroll
      for (int n = 0; n < 4; ++n)
        #pragma unroll
        for (int r = 0; r < 4; ++r)
          cmat[(lr0 + m*16 + r)*136 + wc4 + n*16 + fr] = f2b(acc[m][n][r]);
    __syncthreads();
    const int row = t >> 1, co = (t & 1) * 64;
    #pragma unroll
    for (int hh = 0; hh < 2; ++hh){
      float f[32];
      #pragma unroll
      for (int c4 = 0; c4 < 4; ++c4){
        short8 w = *(const short8*)&cmat[row*136 + co + hh*32 + c4*8];
        #pragma unroll
        for (int k2 = 0; k2 < 8; ++k2) f[c4*8+k2] = b2f((u16)w[k2]);
      }
      float sum = 0.f;
      #pragma unroll
      for (int i2 = 0; i2 < 32; ++i2){ float e = __expf(f[i2]); f[i2] = e; sum += e; }
      float sc = 0.17677669529663689f / sum;
      #pragma unroll
      for (int c4 = 0; c4 < 4; ++c4){
        short8 o;
        #pragma unroll
        for (int k2 = 0; k2 < 8; ++k2) o[k2] = (short)f2b(f[c4*8+k2] * sc);
        *(short8*)&qs[(size_t)(bm+row)*256 + bn*128 + co + hh*32 + c4*8] = o;
      }
    }
  } else {
    // KV block: cols 0-63 = k (2 heads, exp), 64-127 = v. Write TRANSPOSED tiles.
    u16* ekT = pool;               // [64][136]  row=ch(hl*32+dd), col=token
    u16* vT  = pool + 64*136;      // [64][136]  row=ch(hl*32+e),  col=token
    const bool isK = (wc4 == 0);
    #pragma unroll
    for (int m = 0; m < 4; ++m)
      #pragma unroll
      for (int n = 0; n < 4; ++n)
        #pragma unroll
        for (int r = 0; r < 4; ++r){
          int row = lr0 + m*16 + r;      // token
          int csub = n*16 + fr;          // channel within half
          if (isK) ekT[csub*136 + row] = f2b(__expf(acc[m][n][r]));
          else     vT [csub*136 + row] = f2b(acc[m][n][r]);
        }
    __syncthreads();
    // ctx partial via MFMA: wave w -> (hl = w>>1, ti = w&1); C[dd,e] = sum_tok ek*v
    const int hl = wave >> 1, ti = wave & 1;
    const int head = (bn - 2)*2 + hl;
    short8 ones;
    #pragma unroll
    for (int j = 0; j < 8; ++j) ones[j] = (short)0x3F80;
    f32x4 acc2[2] = {}; f32x4 zacc = {};
    #pragma unroll
    for (int kc = 0; kc < 4; ++kc){
      const int ko2 = kc*32 + fkc*8;
      short8 av2 = *(const short8*)&ekT[(hl*32 + ti*16 + fr)*136 + ko2];
      short8 bv0 = *(const short8*)&vT [(hl*32 +         fr)*136 + ko2];
      short8 bv1 = *(const short8*)&vT [(hl*32 + 16 +    fr)*136 + ko2];
      acc2[0] = __builtin_amdgcn_mfma_f32_16x16x32_bf16(av2, bv0, acc2[0], 0, 0, 0);
      acc2[1] = __builtin_amdgcn_mfma_f32_16x16x32_bf16(av2, bv1, acc2[1], 0, 0, 0);
      zacc    = __builtin_amdgcn_mfma_f32_16x16x32_bf16(av2, ones, zacc, 0, 0, 0);
    }
    const size_t pbase = (((size_t)(bm/9216)*72 + ((bm%9216)>>7))*8 + head);
    float* cb = ctxp + pbase*1024;
    const int drow = ti*16 + (lane>>4)*4;
    #pragma unroll
    for (int tj = 0; tj < 2; ++tj)
      #pragma unroll
      for (int rr = 0; rr < 4; ++rr)
        cb[(drow + rr)*32 + tj*16 + fr] = acc2[tj][rr];
    if (fr == 0){
      float* zb = zp + pbase*32;
      #pragma unroll
      for (int rr = 0; rr < 4; ++rr)
        zb[drow + rr] = zacc[rr];
    }
  }
}

// ---------- output GEMM: out = qs @ Weff_f^T + bc + resid, LDS-transpose epilogue ----------
__global__ __launch_bounds__(256, 3) void k_gemm_out(const u16* __restrict__ A, const u16* __restrict__ B,
    float* __restrict__ Cf, const float* __restrict__ bias, const u16* __restrict__ residb,
    int M, int NB, int frame_rows){
  constexpr int K = 256, N = 256, NT = 8;
  __shared__ __align__(16) u16 pool[24576];
  u16* As = pool;
  u16* Bs = pool + 12288;
  const int t = threadIdx.x;
  const int wave = t >> 6, lane = t & 63;
  const int bi = blockIdx.x;
  const int xk = bi & 7, bj = bi >> 3;
  const int bm = (xk + 8*(bj/NB)) * 128, bn = (bj%NB) * 128;
  if (frame_rows > 0) B += (size_t)(bm / frame_rows) * N * K;
  const int srow = wave*32 + (lane>>2);
  const int skel = (((lane&3) ^ ((lane>>3)&3)) << 3);
  const u16* ag = A + (size_t)(bm + srow)*K + skel;
  const u16* bg = B + (size_t)(bn + srow)*K + skel;
  const size_t rstep = (size_t)16*K;
  const int wr = (wave>>1)*64, wc4 = (wave&1)*64;
  const int fr = lane & 15;
  const int fkc = lane >> 4;
  const int koff = ((fkc ^ ((fr>>1)&3)) << 3);
  f32x4 acc[4][4] = {};
  #pragma unroll
  for (int pre = 0; pre < 2; ++pre){
    u16* asl = As + pre*4096 + wave*1024; u16* bsl = Bs + pre*4096 + wave*1024;
    const int k0 = pre*32;
    GLOAD_LDS16(ag + k0,         asl);
    GLOAD_LDS16(ag + rstep + k0, asl + 512);
    GLOAD_LDS16(bg + k0,         bsl);
    GLOAD_LDS16(bg + rstep + k0, bsl + 512);
  }
  #pragma unroll
  for (int it = 0; it < NT; ++it){
    const int cur = it % 3;
    if (it == NT-1) { asm volatile("s_waitcnt vmcnt(0)" ::: "memory"); }
    else            { asm volatile("s_waitcnt vmcnt(4)" ::: "memory"); }
    __builtin_amdgcn_s_barrier();
    __builtin_amdgcn_sched_barrier(0);
    short8 av[4], bv[4];
    #pragma unroll
    for (int m = 0; m < 4; ++m)
      av[m] = *(const short8*)&As[cur*4096 + (wr + m*16 + fr)*32 + koff];
    #pragma unroll
    for (int n = 0; n < 4; ++n)
      bv[n] = *(const short8*)&Bs[cur*4096 + (wc4 + n*16 + fr)*32 + koff];
    if (it + 2 < NT){
      const int nb = (it+2) % 3;
      u16* asl = As + nb*4096 + wave*1024; u16* bsl = Bs + nb*4096 + wave*1024;
      const int k0 = (it+2)*32;
      GLOAD_LDS16(ag + k0,         asl);
      GLOAD_LDS16(ag + rstep + k0, asl + 512);
      GLOAD_LDS16(bg + k0,         bsl);
      GLOAD_LDS16(bg + rstep + k0, bsl + 512);
    }
    __builtin_amdgcn_s_setprio(1);
    #pragma unroll
    for (int m = 0; m < 4; ++m)
      #pragma unroll
      for (int n = 0; n < 4; ++n)
        acc[m][n] = __builtin_amdgcn_mfma_f32_16x16x32_bf16(av[m], bv[n], acc[m][n], 0, 0, 0);
    __builtin_amdgcn_s_setprio(0);
  }
  __syncthreads();
  float* cmatf = (float*)pool;
  const int lr0 = (lane>>4)*4;
  float biasr[32];
  {
    const int c0 = bn + (t&3)*32;
    #pragma unroll
    for (int c4 = 0; c4 < 8; ++c4)
      *(float4*)&biasr[c4*4] = *(const float4*)&bias[c0 + c4*4];
  }
  #pragma unroll
  for (int half = 0; half < 2; ++half){
    if ((wr >> 6) == half){
      #pragma unroll
      for (int m = 0; m < 4; ++m)
        #pragma unroll
        for (int n = 0; n < 4; ++n)
          #pragma unroll
          for (int r = 0; r < 4; ++r)
            cmatf[(lr0 + m*16 + r)*132 + wc4 + n*16 + fr] = acc[m][n][r];
    }
    __syncthreads();
    {
      const int row = t >> 2, seg = (t & 3) * 32;
      const int gr = bm + half*64 + row;
      const size_t gbase = (size_t)gr*256 + bn + seg;
      float v[32];
      #pragma unroll
      for (int c4 = 0; c4 < 8; ++c4)
        *(float4*)&v[c4*4] = *(const float4*)&cmatf[row*132 + seg + c4*4];
      #pragma unroll
      for (int c4 = 0; c4 < 4; ++c4){
        short8 rr = *(const short8*)&residb[gbase + c4*8];
        #pragma unroll
        for (int k2 = 0; k2 < 8; ++k2)
          v[c4*8+k2] += biasr[c4*8+k2] + b2f((u16)rr[k2]);
      }
      #pragma unroll
      for (int c4 = 0; c4 < 8; ++c4)
        *(float4*)&Cf[gbase + c4*4] = *(float4*)&v[c4*4];
    }
    __syncthreads();
  }
}

// ---------- reduce 72 split-partials + apply 1/Z ----------
__global__ __launch_bounds__(256) void k_ctxred(const float* __restrict__ ctxp, const float* __restrict__ zp,
    float* __restrict__ ctx){
  const int h = blockIdx.x, frel = blockIdx.y;
  const int t = threadIdx.x;
  __shared__ float izs[32];
  if (t < 32){
    float zt = 0.f;
    #pragma unroll 8
    for (int q = 0; q < 72; ++q) zt += zp[(((size_t)frel*72 + q)*8 + h)*32 + t];
    izs[t] = 1.0f / zt;
  }
  __syncthreads();
  for (int idx = t; idx < 1024; idx += 256){
    float s = 0.f;
    #pragma unroll 8
    for (int q = 0; q < 72; ++q) s += ctxp[(((size_t)frel*72 + q)*8 + h)*1024 + idx];
    ctx[(size_t)frel*8192 + h*1024 + idx] = s * izs[idx >> 5];
  }
}

// ---------- Weff_f[l, h*32+dd] = sum_e ctx_f[h][dd,e] * Wcomb[l, h*32+e] ----------
__global__ __launch_bounds__(256) void k_weff(const float* __restrict__ ctx, const float* __restrict__ wcf,
    u16* __restrict__ weff){
  int l = blockIdx.x, frel = blockIdx.y, t = threadIdx.x;
  int h = t >> 5, dd = t & 31;
  const float* cr = ctx + (size_t)frel*8192 + h*1024 + dd*32;
  const float* wr = wcf + (size_t)l*256 + h*32;
  float s = 0.f;
  #pragma unroll
  for (int e = 0; e < 32; ++e) s += cr[e] * wr[e];
  weff[((size_t)frel*256 + l)*256 + t] = f2b(s);
}

extern "C" void kernel_launch(void* const* d_in, const int* in_sizes, int n_in,
                              void* d_out, int out_size, void* d_ws, size_t ws_size,
                              hipStream_t stream){
  const float* x     = (const float*)d_in[0];
  const float* w_qkv = (const float*)d_in[1];
  const float* w_out = (const float*)d_in[2];
  const float* b_out = (const float*)d_in[3];
  const float* w_lin = (const float*)d_in[4];
  const float* b_lin = (const float*)d_in[5];
  float* out = (float*)d_out;

  char* p = (char*)d_ws;
  u16*   wqb   = (u16*)p;   p += (size_t)768*256*2;
  float* wcf   = (float*)p; p += (size_t)256*256*4;
  float* bc    = (float*)p; p += 256*4;
  float* zpb   = (float*)p; p += (size_t)8*72*8*32*4;
  float* ctxpb = (float*)p; p += (size_t)8*72*8*1024*4;
  float* ctxb  = (float*)p; p += (size_t)8*8192*4;
  u16*   weffb = (u16*)p;   p += (size_t)8*256*256*2;
  size_t fixed = (size_t)(p - (char*)d_ws);
  size_t per_frame = (size_t)2 * 9216*256*2;   // xb + qs
  int chunk = (ws_size >= fixed + 8*per_frame) ? 8 : 1;
  u16* xb  = (u16*)p;
  u16* qsb = xb  + (size_t)chunk*9216*256;

  // weight prep (once)
  hipLaunchKernelGGL(k_cvtw, dim3(768), dim3(256), 0, stream, w_qkv, wqb);
  hipLaunchKernelGGL(k_prepw, dim3(256), dim3(256), 0, stream, w_lin, w_out, b_out, b_lin, wcf, bc);

  for (int f0 = 0; f0 < 8; f0 += chunk){
    const float* xc = x  + (size_t)f0*9216*256;
    float*       oc = out + (size_t)f0*9216*256;
    const int M = chunk * 9216;
    const int n4 = M * 256 / 4;
    hipLaunchKernelGGL(k_cvt, dim3((n4 + 255)/256), dim3(256), 0, stream, (const float4*)xc, (ushort4*)xb, n4);
    hipLaunchKernelGGL(k_gemm_qkv, dim3((M/128)*6), dim3(256), 0, stream,
                       xb, wqb, qsb, ctxpb + (size_t)f0*72*8*1024, zpb + (size_t)f0*72*8*32, M);
    hipLaunchKernelGGL(k_ctxred, dim3(8, chunk), dim3(256), 0, stream,
                       ctxpb + (size_t)f0*72*8*1024, zpb + (size_t)f0*72*8*32, ctxb + (size_t)f0*8192);
    hipLaunchKernelGGL(k_weff, dim3(256, chunk), dim3(256), 0, stream,
                       ctxb + (size_t)f0*8192, wcf, weffb + (size_t)f0*256*256);
    hipLaunchKernelGGL(k_gemm_out, dim3((M/128)*2), dim3(256), 0, stream,
                       qsb, weffb + (size_t)f0*256*256, oc, bc, xb,
                       M, 2, (chunk == 8) ? 9216 : 0);
  }
}